// Round 6
// baseline (618.428 us; speedup 1.0000x reference)
//
#include <hip/hip_runtime.h>
#include <hip/hip_cooperative_groups.h>

namespace cg = cooperative_groups;

#define EPS 1e-5f

// B=32, C=256, CC=64, template 14x14, search 64x64, K=7, 32 groups (2ch/group)
// Fused v3: grid-stride phases, occupancy-queried cooperative launch, split-kernel fallback.

typedef __attribute__((ext_vector_type(8))) short short8;
typedef __attribute__((ext_vector_type(4))) float floatx4;

__device__ __forceinline__ unsigned short f2bf(float x) {
    union { float f; unsigned u; } v; v.f = x;
    unsigned r = v.u + 0x7FFFu + ((v.u >> 16) & 1u);   // RNE
    return (unsigned short)(r >> 16);
}
__device__ __forceinline__ float bf2f(unsigned short h) {
    union { unsigned u; float f; } v; v.u = ((unsigned)h) << 16;
    return v.f;
}

struct Params {
    const float* tmpl; const float* search;
    const float* w_t; const float* gn_t_w; const float* gn_t_b;
    const float* w_s; const float* gn_s_w; const float* gn_s_b;
    const float* w_p1; const float* gn_p_w; const float* gn_p_b;
    const float* w_p2; const float* b_p2;
    float* TG; float* TK;
    float* P1; float* P2;
    unsigned short* WPK; unsigned short* WSB;
    float* SRAW;
    unsigned short* CORRB; unsigned short* YRAW;
    float* out;
};

__global__ __launch_bounds__(256, 4) void fused(Params P)
{
    const int tid = threadIdx.x;
    const int blk = blockIdx.x;
    const int NB = gridDim.x;
    cg::grid_group grid = cg::this_grid();
    __shared__ __align__(16) char smem[35840];

    // ================= P0: template path (jobs 0-255) + weight packing (jobs 256-463) =================
    for (int job = blk; job < 464; job += NB) {
        if (job < 256) {
            int b = job >> 3, h = job & 7;   // h: eighth of oc (8 oc)
            float (*Xs)[200] = (float(*)[200])smem;              // 25600 B
            float (*T0)[200] = (float(*)[200])(smem + 25600);    // 6400 B
            float* sums  = (float*)(smem + 32000);
            float* sumsq = (float*)(smem + 32032);
            float* Ac    = (float*)(smem + 32064);
            float* Bb    = (float*)(smem + 32096);
            float acc[8];
            #pragma unroll
            for (int o = 0; o < 8; ++o) acc[o] = 0.f;
            const float* wb = P.w_t + (h * 8) * 256;
            const float* tb = P.tmpl + b * 50176;
            int p = tid;
            for (int chunk = 0; chunk < 8; ++chunk) {
                __syncthreads();
                #pragma unroll
                for (int j = 0; j < 7; ++j) {
                    int f4 = tid + (j << 8);
                    if (f4 < 1568) {                        // 32 rows x 49 float4
                        int ic = f4 / 49, px4 = (f4 - ic * 49) << 2;
                        float4 v = *(const float4*)(tb + (chunk * 32 + ic) * 196 + px4);
                        *(float4*)&Xs[ic][px4] = v;
                    }
                }
                __syncthreads();
                if (p < 196) {
                    for (int cc = 0; cc < 32; ++cc) {
                        float xv = Xs[cc][p];
                        #pragma unroll
                        for (int o = 0; o < 8; ++o)
                            acc[o] += xv * wb[o * 256 + chunk * 32 + cc];
                    }
                }
            }
            __syncthreads();
            if (p < 196) {
                #pragma unroll
                for (int o = 0; o < 8; ++o) T0[o][p] = acc[o];
            }
            __syncthreads();
            if (tid < 128) {   // 16 lanes per channel
                int c = tid >> 4, part = tid & 15;
                float s = 0.f, s2 = 0.f;
                for (int qq = part; qq < 196; qq += 16) { float v = T0[c][qq]; s += v; s2 += v * v; }
                #pragma unroll
                for (int off = 1; off < 16; off <<= 1) {
                    s += __shfl_xor(s, off, 16); s2 += __shfl_xor(s2, off, 16);
                }
                if (part == 0) { sums[c] = s; sumsq[c] = s2; }
            }
            __syncthreads();
            if (tid < 4) {   // group = channel pair, both in this job
                float S  = sums[2 * tid] + sums[2 * tid + 1];
                float S2 = sumsq[2 * tid] + sumsq[2 * tid + 1];
                float mean = S * (1.f / 392.f);
                float var  = S2 * (1.f / 392.f) - mean * mean;
                float inv  = rsqrtf(var + EPS);
                for (int e = 0; e < 2; ++e) {
                    int c = 2 * tid + e, gc = h * 8 + c;
                    float a = P.gn_t_w[gc] * inv;
                    Ac[c] = a; Bb[c] = P.gn_t_b[gc] - mean * a;
                }
            }
            __syncthreads();
            if (p < 196) {
                #pragma unroll
                for (int o = 0; o < 8; ++o) {
                    float v = Ac[o] * T0[o][p] + Bb[o];
                    T0[o][p] = v > 0.f ? v : 0.f;
                }
            }
            __syncthreads();
            if (tid < 128) {
                int c = tid >> 4, part = tid & 15, gc = h * 8 + c;
                float s = 0.f;
                for (int qq = part; qq < 196; qq += 16) s += T0[c][qq];
                #pragma unroll
                for (int off = 1; off < 16; off <<= 1) s += __shfl_xor(s, off, 16);
                if (part == 0) P.TG[b * 64 + gc] = s * (1.f / 196.f);
                for (int t = part; t < 49; t += 16) {
                    int ky = t / 7, kx = t - 7 * ky;
                    float v = T0[c][(2 * ky) * 14 + 2 * kx]     + T0[c][(2 * ky) * 14 + 2 * kx + 1]
                            + T0[c][(2 * ky + 1) * 14 + 2 * kx] + T0[c][(2 * ky + 1) * 14 + 2 * kx + 1];
                    P.TK[(b * 64 + gc) * 49 + t] = v * 0.25f;
                }
            }
            __syncthreads();
        } else {
            int idx = ((job - 256) << 8) + tid;
            if (idx < 16384) {
                P.WSB[idx] = f2bf(P.w_s[idx]);
            } else if (idx < 53248) {
                int i = idx - 16384;
                int c = i >> 11, rem = i & 2047, oc = rem >> 5, k = rem & 31;
                int tap = c >> 1, ic = ((c & 1) << 5) + k;
                P.WPK[i] = f2bf(P.w_p1[oc * 576 + ic * 9 + tap]);
            }
        }
    }
    grid.sync();

    // ================= P1: search conv1x1 MFMA + fused GN stat partials (1024 jobs) =================
    {
        short* tile = (short*)smem;                          // 16384 B
        float (*Ps)[64]  = (float(*)[64])(smem + 16384);     // 1024 B
        float (*Ps2)[64] = (float(*)[64])(smem + 17408);     // 1024 B
        int wave = tid >> 6, lane = tid & 63, q = lane >> 4, l15 = lane & 15;
        for (int job = blk; job < 1024; job += NB) {
            int b = job >> 5, p0 = (job & 31) << 7;
            floatx4 acc[2][4];
            #pragma unroll
            for (int i = 0; i < 2; ++i)
                #pragma unroll
                for (int mt = 0; mt < 4; ++mt) acc[i][mt] = (floatx4){0.f, 0.f, 0.f, 0.f};

            int pxq = (tid & 31) << 2;     // px base (4 consecutive px per thread)
            int icr = tid >> 5;            // ic group 0..7 (8 consecutive ic per thread)
            const float* xb = P.search + ((long)b << 20) + p0 + pxq;
            float4 L[8];
            #pragma unroll
            for (int i = 0; i < 8; ++i)
                L[i] = *(const float4*)(xb + ((long)((icr << 3) + i) << 12));
            for (int chunk = 0; chunk < 4; ++chunk) {           // 64 ic per chunk
                __syncthreads();   // prior MFMA reads of tile complete
                #pragma unroll
                for (int j = 0; j < 4; ++j) {
                    int px = pxq + j;
                    short8 s8;
                    #pragma unroll
                    for (int e = 0; e < 8; ++e) s8[e] = (short)f2bf(((const float*)&L[e])[j]);
                    int sw = icr ^ (px & 7);
                    *(short8*)&tile[(px << 6) + (sw << 3)] = s8;
                }
                __syncthreads();
                if (chunk < 3) {   // prefetch next chunk while MFMA runs
                    #pragma unroll
                    for (int i = 0; i < 8; ++i)
                        L[i] = *(const float4*)(xb + ((long)(((chunk + 1) << 6) + (icr << 3) + i) << 12));
                }
                #pragma unroll
                for (int kq = 0; kq < 2; ++kq) {                // 32-ic MFMA chunks
                    short8 afr[4], bfr[2];
                    int kbase = (chunk << 6) + (kq << 5) + (q << 3);
                    #pragma unroll
                    for (int mt = 0; mt < 4; ++mt)
                        afr[mt] = *(const short8*)(P.WSB + ((mt << 4) + l15) * 256 + kbase);
                    #pragma unroll
                    for (int i = 0; i < 2; ++i) {
                        int px = (((wave << 1) + i) << 4) + l15;
                        int sw = ((kq << 2) + q) ^ (px & 7);
                        bfr[i] = *(const short8*)&tile[(px << 6) + (sw << 3)];
                    }
                    #pragma unroll
                    for (int i = 0; i < 2; ++i)
                        #pragma unroll
                        for (int mt = 0; mt < 4; ++mt)
                            acc[i][mt] = __builtin_amdgcn_mfma_f32_16x16x32_bf16(afr[mt], bfr[i], acc[i][mt], 0, 0, 0);
                }
            }
            float* ob = P.SRAW + ((long)b << 18) + p0;
            #pragma unroll
            for (int i = 0; i < 2; ++i) {
                int pxb = ((wave << 1) + i) << 4;
                #pragma unroll
                for (int mt = 0; mt < 4; ++mt)
                    #pragma unroll
                    for (int r = 0; r < 4; ++r) {
                        int oc = (mt << 4) + (q << 2) + r;
                        ob[(oc << 12) + pxb + l15] = acc[i][mt][r];
                    }
            }
            #pragma unroll
            for (int mt = 0; mt < 4; ++mt) {
                #pragma unroll
                for (int r = 0; r < 4; ++r) {
                    float s = 0.f, s2 = 0.f;
                    #pragma unroll
                    for (int i = 0; i < 2; ++i) { float v = acc[i][mt][r]; s += v; s2 += v * v; }
                    #pragma unroll
                    for (int off = 1; off < 16; off <<= 1) {
                        s  += __shfl_xor(s, off, 64);
                        s2 += __shfl_xor(s2, off, 64);
                    }
                    if (l15 == 0) {
                        int oc = (mt << 4) + (q << 2) + r;
                        Ps[wave][oc] = s; Ps2[wave][oc] = s2;
                    }
                }
            }
            __syncthreads();
            if (tid < 64) {
                float s  = Ps[0][tid] + Ps[1][tid] + Ps[2][tid] + Ps[3][tid];
                float s2 = Ps2[0][tid] + Ps2[1][tid] + Ps2[2][tid] + Ps2[3][tid];
                int idx = (((b << 5) + (job & 31)) << 6) + tid;
                P.P1[idx] = s; P.P2[idx] = s2;
            }
        }
    }
    grid.sync();

    // ================= P3: corr = s*t_global + depthwise7x7 -> bf16 NCHW (2048 planes) =================
    {
        float* t4   = (float*)smem;            // 19600 B
        float* ker  = (float*)(smem + 19600);  // 196 B
        float* fin4 = (float*)(smem + 19808);
        float* sAB  = (float*)(smem + 19824);
        for (int bc = blk; bc < 2048; bc += NB) {
            int b = bc >> 6, c = bc & 63;
            __syncthreads();   // previous rep fully done with t4/sAB
            if (tid < 32) {   // finalize GN coefs from 32 tile-partials x 2 channels
                int ch = (c & ~1) + (tid >> 4), k = tid & 15;
                int base = ((b << 5) + k) << 6;
                float s  = P.P1[base + ch] + P.P1[base + (16 << 6) + ch];
                float s2 = P.P2[base + ch] + P.P2[base + (16 << 6) + ch];
                #pragma unroll
                for (int off = 1; off < 16; off <<= 1) {
                    s += __shfl_xor(s, off, 16); s2 += __shfl_xor(s2, off, 16);
                }
                if (k == 0) { fin4[tid >> 4] = s; fin4[2 + (tid >> 4)] = s2; }
            }
            for (int i = tid; i < 4900; i += 256) t4[i] = 0.f;
            if (tid < 49) ker[tid] = P.TK[bc * 49 + tid];
            __syncthreads();
            if (tid == 0) {
                float S = fin4[0] + fin4[1], S2 = fin4[2] + fin4[3];
                float mean = S * (1.f / 8192.f);
                float var  = S2 * (1.f / 8192.f) - mean * mean;
                float inv  = rsqrtf(var + EPS);
                float a = P.gn_s_w[c] * inv;
                sAB[0] = a; sAB[1] = P.gn_s_b[c] - mean * a;
            }
            __syncthreads();
            float a = sAB[0], bb = sAB[1], tg = P.TG[bc];
            const float4* sb4 = (const float4*)(P.SRAW + ((long)bc << 12));
            for (int i4 = tid; i4 < 1024; i4 += 256) {
                float4 v4 = sb4[i4];
                int y = i4 >> 4, xx = (i4 & 15) << 2;
                float* dst = &t4[(y + 3) * 70 + xx + 3];
                float v;
                v = a * v4.x + bb; dst[0] = v > 0.f ? v : 0.f;
                v = a * v4.y + bb; dst[1] = v > 0.f ? v : 0.f;
                v = a * v4.z + bb; dst[2] = v > 0.f ? v : 0.f;
                v = a * v4.w + bb; dst[3] = v > 0.f ? v : 0.f;
            }
            __syncthreads();
            int x = tid & 63, ys = (tid >> 6) << 4;
            float acc[16];
            #pragma unroll
            for (int j = 0; j < 16; ++j) acc[j] = 0.f;
            #pragma unroll
            for (int kx = 0; kx < 7; ++kx) {
                float col[22];
                #pragma unroll
                for (int j = 0; j < 22; ++j) col[j] = t4[(ys + j) * 70 + x + kx];
                #pragma unroll
                for (int ky = 0; ky < 7; ++ky) {
                    float kv = ker[ky * 7 + kx];
                    #pragma unroll
                    for (int j = 0; j < 16; ++j) acc[j] += kv * col[j + ky];
                }
            }
            unsigned short* ob = P.CORRB + ((long)bc << 12);
            #pragma unroll
            for (int j = 0; j < 16; ++j) {
                float sval = t4[(ys + j + 3) * 70 + x + 3];
                ob[((ys + j) << 6) + x] = f2bf(acc[j] + sval * tg);
            }
        }
    }
    grid.sync();

    // ================= P4: conv3x3 MFMA reading NCHW bf16 corr (transpose in staging, 1024 jobs) =================
    {
        short* tile = (short*)smem;                          // 33792 B
        float (*Ys)[64]  = (float(*)[64])(smem + 33792);     // 1024 B
        float (*Ys2)[64] = (float(*)[64])(smem + 34816);     // 1024 B
        int wave = tid >> 6, lane = tid & 63, q = lane >> 4, l15 = lane & 15;
        for (int job = blk; job < 1024; job += NB) {
            int b = job >> 5, py0 = (job & 31) << 1;
            {
                int row = tid >> 6, ic = tid & 63;   // wave = one tile row, lane = ic
                int py = py0 - 1 + row;
                int rbase = (row * 66) << 6;
                int icblk = ic >> 3, icl = ic & 7;
                if (py >= 0 && py < 64) {
                    const uint4* src = (const uint4*)(P.CORRB + (((long)(b << 6) + ic) << 12) + (py << 6));
                    #pragma unroll
                    for (int c8 = 0; c8 < 8; ++c8) {
                        uint4 u = src[c8];
                        const unsigned short* us = (const unsigned short*)&u;
                        #pragma unroll
                        for (int e = 0; e < 8; ++e) {
                            int col = (c8 << 3) + e + 1;
                            int sw = icblk ^ (col & 7);
                            tile[rbase + (col << 6) + (sw << 3) + icl] = us[e];
                        }
                    }
                } else {
                    for (int col = 1; col <= 64; ++col) {
                        int sw = icblk ^ (col & 7);
                        tile[rbase + (col << 6) + (sw << 3) + icl] = 0;
                    }
                }
                tile[rbase + (icblk << 3) + icl] = 0;
                tile[rbase + (65 << 6) + (((icblk ^ 1) << 3)) + icl] = 0;
            }
            __syncthreads();

            floatx4 acc[2][4];
            #pragma unroll
            for (int i = 0; i < 2; ++i)
                #pragma unroll
                for (int ot = 0; ot < 4; ++ot) acc[i][ot] = (floatx4){0.f, 0.f, 0.f, 0.f};

            int pt0 = wave << 1;
            int rowb[2], colb[2];
            #pragma unroll
            for (int i = 0; i < 2; ++i) {
                int p = ((pt0 + i) << 4) + l15;
                rowb[i] = p >> 6;
                colb[i] = p & 63;
            }
            #pragma unroll
            for (int c = 0; c < 18; ++c) {
                const int tap = c >> 1, ky = tap / 3, kx = tap % 3, h = c & 1;
                short8 bfr[4], afr[2];
                #pragma unroll
                for (int ot = 0; ot < 4; ++ot)
                    bfr[ot] = *(const short8*)(P.WPK + ((c << 6) + (ot << 4) + l15) * 32 + (q << 3));
                #pragma unroll
                for (int i = 0; i < 2; ++i) {
                    int row = rowb[i] + ky, col = colb[i] + kx;
                    int sw = ((h << 2) + q) ^ (col & 7);
                    afr[i] = *(const short8*)&tile[((row * 66 + col) << 6) + (sw << 3)];
                }
                #pragma unroll
                for (int i = 0; i < 2; ++i)
                    #pragma unroll
                    for (int ot = 0; ot < 4; ++ot)
                        acc[i][ot] = __builtin_amdgcn_mfma_f32_16x16x32_bf16(afr[i], bfr[ot], acc[i][ot], 0, 0, 0);
            }
            #pragma unroll
            for (int i = 0; i < 2; ++i) {
                #pragma unroll
                for (int r = 0; r < 4; ++r) {
                    int p = ((pt0 + i) << 4) + (q << 2) + r;
                    int py = py0 + (p >> 6), pxc = p & 63;
                    int base = ((b << 12) + (py << 6) + pxc) << 6;
                    #pragma unroll
                    for (int ot = 0; ot < 4; ++ot)
                        P.YRAW[base + (ot << 4) + l15] = f2bf(acc[i][ot][r]);
                }
            }
            #pragma unroll
            for (int ot = 0; ot < 4; ++ot) {
                float s = 0.f, s2 = 0.f;
                #pragma unroll
                for (int i = 0; i < 2; ++i)
                    #pragma unroll
                    for (int r = 0; r < 4; ++r) { float v = acc[i][ot][r]; s += v; s2 += v * v; }
                s += __shfl_xor(s, 16, 64); s2 += __shfl_xor(s2, 16, 64);
                s += __shfl_xor(s, 32, 64); s2 += __shfl_xor(s2, 32, 64);
                if (lane < 16) { Ys[wave][(ot << 4) + lane] = s; Ys2[wave][(ot << 4) + lane] = s2; }
            }
            __syncthreads();
            if (tid < 64) {
                float s  = Ys[0][tid] + Ys[1][tid] + Ys[2][tid] + Ys[3][tid];
                float s2 = Ys2[0][tid] + Ys2[1][tid] + Ys2[2][tid] + Ys2[3][tid];
                int idx = (((b << 5) + (job & 31)) << 6) + tid;
                P.P1[idx] = s; P.P2[idx] = s2;
            }
            __syncthreads();
        }
    }
    grid.sync();

    // ================= P5: epilogue on NHWC bf16 y (inline y-GN finalize, 1024 jobs) =================
    {
        float* sA = (float*)smem;
        float* sB = (float*)(smem + 256);
        int wave = tid >> 6, lane = tid & 63;
        for (int job = blk; job < 1024; job += NB) {
            int b = job >> 5;
            int px0 = (job & 31) << 7;
            if (tid < 64) {
                int c = tid;
                float s = 0.f, s2 = 0.f;
                for (int t = 0; t < 32; ++t) {
                    int idx = (((b << 5) + t) << 6) + c;
                    s += P.P1[idx]; s2 += P.P2[idx];
                }
                float sp = __shfl_xor(s, 1, 64), s2p = __shfl_xor(s2, 1, 64);
                float S = s + sp, S2 = s2 + s2p;
                float mean = S * (1.f / 8192.f);
                float var  = S2 * (1.f / 8192.f) - mean * mean;
                float inv  = rsqrtf(var + EPS);
                float a = P.gn_p_w[c] * inv;
                sA[c] = a; sB[c] = P.gn_p_b[c] - mean * a;
            }
            __syncthreads();
            int ocp = lane & 31, ph = lane >> 5;
            int c0 = 2 * ocp;
            float a0 = sA[c0],     b0 = sB[c0],     w20 = P.w_p2[c0];
            float a1 = sA[c0 + 1], b1 = sB[c0 + 1], w21 = P.w_p2[c0 + 1];
            float bias = P.b_p2[0];
            const unsigned* yp = (const unsigned*)P.YRAW;
            for (int i = 0; i < 16; ++i) {
                int px = px0 + (i << 3) + (wave << 1) + ph;
                unsigned u = yp[(((b << 12) + px) << 5) + ocp];
                float f0 = bf2f((unsigned short)(u & 0xFFFF));
                float f1 = bf2f((unsigned short)(u >> 16));
                float v0 = a0 * f0 + b0; v0 = v0 > 0.f ? v0 : 0.f;
                float v1 = a1 * f1 + b1; v1 = v1 > 0.f ? v1 : 0.f;
                float val = w20 * v0 + w21 * v1;
                #pragma unroll
                for (int m = 16; m >= 1; m >>= 1) val += __shfl_xor(val, m, 64);
                if (ocp == 0) P.out[(b << 12) + px] = val + bias;
            }
            __syncthreads();   // sA/sB reused next rep
        }
    }
}

// ======================= fallback split pipeline (round-4, known-pass) =======================

__global__ __launch_bounds__(256) void k1_template(
    const float* __restrict__ tmpl, const float* __restrict__ w_t,
    const float* __restrict__ gnw, const float* __restrict__ gnb,
    float* __restrict__ t_global, float* __restrict__ t_kernel)
{
    int b = blockIdx.x >> 3, h = blockIdx.x & 7;
    int tid = threadIdx.x;
    __shared__ float Xs[32][200];
    __shared__ float T0[8][200];
    __shared__ float sums[8], sumsq[8], Ac[8], Bb[8];
    float acc[8];
    #pragma unroll
    for (int o = 0; o < 8; ++o) acc[o] = 0.f;
    const float* wb = w_t + (h * 8) * 256;
    const float* tb = tmpl + b * 50176;
    int p = tid;
    for (int chunk = 0; chunk < 8; ++chunk) {
        __syncthreads();
        #pragma unroll
        for (int j = 0; j < 7; ++j) {
            int f4 = tid + (j << 8);
            if (f4 < 1568) {
                int ic = f4 / 49, px4 = (f4 - ic * 49) << 2;
                float4 v = *(const float4*)(tb + (chunk * 32 + ic) * 196 + px4);
                *(float4*)&Xs[ic][px4] = v;
            }
        }
        __syncthreads();
        if (p < 196) {
            for (int cc = 0; cc < 32; ++cc) {
                float xv = Xs[cc][p];
                #pragma unroll
                for (int o = 0; o < 8; ++o)
                    acc[o] += xv * wb[o * 256 + chunk * 32 + cc];
            }
        }
    }
    __syncthreads();
    if (p < 196) {
        #pragma unroll
        for (int o = 0; o < 8; ++o) T0[o][p] = acc[o];
    }
    __syncthreads();
    if (tid < 128) {
        int c = tid >> 4, part = tid & 15;
        float s = 0.f, s2 = 0.f;
        for (int qq = part; qq < 196; qq += 16) { float v = T0[c][qq]; s += v; s2 += v * v; }
        #pragma unroll
        for (int off = 1; off < 16; off <<= 1) {
            s += __shfl_xor(s, off, 16); s2 += __shfl_xor(s2, off, 16);
        }
        if (part == 0) { sums[c] = s; sumsq[c] = s2; }
    }
    __syncthreads();
    if (tid < 4) {
        float S  = sums[2 * tid] + sums[2 * tid + 1];
        float S2 = sumsq[2 * tid] + sumsq[2 * tid + 1];
        float mean = S * (1.f / 392.f);
        float var  = S2 * (1.f / 392.f) - mean * mean;
        float inv  = rsqrtf(var + EPS);
        for (int e = 0; e < 2; ++e) {
            int c = 2 * tid + e, gc = h * 8 + c;
            float a = gnw[gc] * inv;
            Ac[c] = a; Bb[c] = gnb[gc] - mean * a;
        }
    }
    __syncthreads();
    if (p < 196) {
        #pragma unroll
        for (int o = 0; o < 8; ++o) {
            float v = Ac[o] * T0[o][p] + Bb[o];
            T0[o][p] = v > 0.f ? v : 0.f;
        }
    }
    __syncthreads();
    if (tid < 128) {
        int c = tid >> 4, part = tid & 15, gc = h * 8 + c;
        float s = 0.f;
        for (int qq = part; qq < 196; qq += 16) s += T0[c][qq];
        #pragma unroll
        for (int off = 1; off < 16; off <<= 1) s += __shfl_xor(s, off, 16);
        if (part == 0) t_global[b * 64 + gc] = s * (1.f / 196.f);
        for (int t = part; t < 49; t += 16) {
            int ky = t / 7, kx = t - 7 * ky;
            float v = T0[c][(2 * ky) * 14 + 2 * kx]     + T0[c][(2 * ky) * 14 + 2 * kx + 1]
                    + T0[c][(2 * ky + 1) * 14 + 2 * kx] + T0[c][(2 * ky + 1) * 14 + 2 * kx + 1];
            t_kernel[(b * 64 + gc) * 49 + t] = v * 0.25f;
        }
    }
}

__global__ __launch_bounds__(256) void k_pack(
    const float* __restrict__ w_s, unsigned short* __restrict__ wsb,
    const float* __restrict__ w1, unsigned short* __restrict__ wpk)
{
    int blk = blockIdx.x;
    if (blk < 64) {
        int i = blk * 256 + threadIdx.x;
        wsb[i] = f2bf(w_s[i]);
    } else {
        int i = (blk - 64) * 256 + threadIdx.x;
        if (i < 36864) {
            int c = i >> 11;
            int rem = i & 2047;
            int oc = rem >> 5;
            int k = rem & 31;
            int tap = c >> 1;
            int ic = ((c & 1) << 5) + k;
            wpk[i] = f2bf(w1[oc * 576 + ic * 9 + tap]);
        }
    }
}

__global__ __launch_bounds__(256) void k2_mfma(
    const float* __restrict__ x, const unsigned short* __restrict__ wsb,
    float* __restrict__ sraw, float* __restrict__ P1, float* __restrict__ P2)
{
    int b = blockIdx.y, p0 = blockIdx.x << 7;
    int tid = threadIdx.x;
    int wave = tid >> 6, lane = tid & 63, q = lane >> 4, l15 = lane & 15;
    __shared__ short tile[128 * 64];
    __shared__ float Ps[4][64], Ps2[4][64];

    floatx4 acc[2][4];
    #pragma unroll
    for (int i = 0; i < 2; ++i)
        #pragma unroll
        for (int mt = 0; mt < 4; ++mt) acc[i][mt] = (floatx4){0.f, 0.f, 0.f, 0.f};

    int pxq = (tid & 31) << 2;
    int icr = tid >> 5;
    const float* xb = x + ((long)b << 20) + p0 + pxq;
    float4 L[8];
    #pragma unroll
    for (int i = 0; i < 8; ++i)
        L[i] = *(const float4*)(xb + ((long)((icr << 3) + i) << 12));
    for (int chunk = 0; chunk < 4; ++chunk) {
        __syncthreads();
        #pragma unroll
        for (int j = 0; j < 4; ++j) {
            int px = pxq + j;
            short8 s8;
            #pragma unroll
            for (int e = 0; e < 8; ++e) s8[e] = (short)f2bf(((const float*)&L[e])[j]);
            int sw = icr ^ (px & 7);
            *(short8*)&tile[(px << 6) + (sw << 3)] = s8;
        }
        __syncthreads();
        if (chunk < 3) {
            #pragma unroll
            for (int i = 0; i < 8; ++i)
                L[i] = *(const float4*)(xb + ((long)(((chunk + 1) << 6) + (icr << 3) + i) << 12));
        }
        #pragma unroll
        for (int kq = 0; kq < 2; ++kq) {
            short8 afr[4], bfr[2];
            int kbase = (chunk << 6) + (kq << 5) + (q << 3);
            #pragma unroll
            for (int mt = 0; mt < 4; ++mt)
                afr[mt] = *(const short8*)(wsb + ((mt << 4) + l15) * 256 + kbase);
            #pragma unroll
            for (int i = 0; i < 2; ++i) {
                int px = (((wave << 1) + i) << 4) + l15;
                int sw = ((kq << 2) + q) ^ (px & 7);
                bfr[i] = *(const short8*)&tile[(px << 6) + (sw << 3)];
            }
            #pragma unroll
            for (int i = 0; i < 2; ++i)
                #pragma unroll
                for (int mt = 0; mt < 4; ++mt)
                    acc[i][mt] = __builtin_amdgcn_mfma_f32_16x16x32_bf16(afr[mt], bfr[i], acc[i][mt], 0, 0, 0);
        }
    }
    float* ob = sraw + ((long)b << 18) + p0;
    #pragma unroll
    for (int i = 0; i < 2; ++i) {
        int pxb = ((wave << 1) + i) << 4;
        #pragma unroll
        for (int mt = 0; mt < 4; ++mt)
            #pragma unroll
            for (int r = 0; r < 4; ++r) {
                int oc = (mt << 4) + (q << 2) + r;
                ob[(oc << 12) + pxb + l15] = acc[i][mt][r];
            }
    }
    #pragma unroll
    for (int mt = 0; mt < 4; ++mt) {
        #pragma unroll
        for (int r = 0; r < 4; ++r) {
            float s = 0.f, s2 = 0.f;
            #pragma unroll
            for (int i = 0; i < 2; ++i) { float v = acc[i][mt][r]; s += v; s2 += v * v; }
            #pragma unroll
            for (int off = 1; off < 16; off <<= 1) {
                s  += __shfl_xor(s, off, 64);
                s2 += __shfl_xor(s2, off, 64);
            }
            if (l15 == 0) {
                int oc = (mt << 4) + (q << 2) + r;
                Ps[wave][oc] = s; Ps2[wave][oc] = s2;
            }
        }
    }
    __syncthreads();
    if (tid < 64) {
        float s  = Ps[0][tid] + Ps[1][tid] + Ps[2][tid] + Ps[3][tid];
        float s2 = Ps2[0][tid] + Ps2[1][tid] + Ps2[2][tid] + Ps2[3][tid];
        int idx = (((b << 5) + blockIdx.x) << 6) + tid;
        P1[idx] = s; P2[idx] = s2;
    }
}

__global__ __launch_bounds__(256) void k4_corr(
    const float* __restrict__ sraw, const float* __restrict__ P1, const float* __restrict__ P2,
    const float* __restrict__ gnw, const float* __restrict__ gnb,
    const float* __restrict__ t_global, const float* __restrict__ t_kernel,
    unsigned short* __restrict__ corr)
{
    int bc = blockIdx.x;
    int b = bc >> 6, c = bc & 63;
    int tid = threadIdx.x;
    __shared__ float t4[70 * 70];
    __shared__ float ker[49];
    __shared__ float fin4[4];
    __shared__ float sAB[2];
    if (tid < 32) {
        int ch = (c & ~1) + (tid >> 4), k = tid & 15;
        int base = ((b << 5) + k) << 6;
        float s  = P1[base + ch] + P1[base + (16 << 6) + ch];
        float s2 = P2[base + ch] + P2[base + (16 << 6) + ch];
        #pragma unroll
        for (int off = 1; off < 16; off <<= 1) {
            s += __shfl_xor(s, off, 16); s2 += __shfl_xor(s2, off, 16);
        }
        if (k == 0) { fin4[tid >> 4] = s; fin4[2 + (tid >> 4)] = s2; }
    }
    for (int i = tid; i < 4900; i += 256) t4[i] = 0.f;
    if (tid < 49) ker[tid] = t_kernel[bc * 49 + tid];
    __syncthreads();
    if (tid == 0) {
        float S = fin4[0] + fin4[1], S2 = fin4[2] + fin4[3];
        float mean = S * (1.f / 8192.f);
        float var  = S2 * (1.f / 8192.f) - mean * mean;
        float inv  = rsqrtf(var + EPS);
        float a = gnw[c] * inv;
        sAB[0] = a; sAB[1] = gnb[c] - mean * a;
    }
    __syncthreads();
    float a = sAB[0], bb = sAB[1], tg = t_global[bc];
    const float4* sb4 = (const float4*)(sraw + ((long)bc << 12));
    for (int i4 = tid; i4 < 1024; i4 += 256) {
        float4 v4 = sb4[i4];
        int y = i4 >> 4, xx = (i4 & 15) << 2;
        float* dst = &t4[(y + 3) * 70 + xx + 3];
        float v;
        v = a * v4.x + bb; dst[0] = v > 0.f ? v : 0.f;
        v = a * v4.y + bb; dst[1] = v > 0.f ? v : 0.f;
        v = a * v4.z + bb; dst[2] = v > 0.f ? v : 0.f;
        v = a * v4.w + bb; dst[3] = v > 0.f ? v : 0.f;
    }
    __syncthreads();
    int x = tid & 63, ys = (tid >> 6) << 4;
    float acc[16];
    #pragma unroll
    for (int j = 0; j < 16; ++j) acc[j] = 0.f;
    #pragma unroll
    for (int kx = 0; kx < 7; ++kx) {
        float col[22];
        #pragma unroll
        for (int j = 0; j < 22; ++j) col[j] = t4[(ys + j) * 70 + x + kx];
        #pragma unroll
        for (int ky = 0; ky < 7; ++ky) {
            float kv = ker[ky * 7 + kx];
            #pragma unroll
            for (int j = 0; j < 16; ++j) acc[j] += kv * col[j + ky];
        }
    }
    unsigned short* ob = corr + ((long)bc << 12);
    #pragma unroll
    for (int j = 0; j < 16; ++j) {
        float sval = t4[(ys + j + 3) * 70 + x + 3];
        ob[((ys + j) << 6) + x] = f2bf(acc[j] + sval * tg);
    }
}

__global__ __launch_bounds__(256) void k5_mfma(
    const unsigned short* __restrict__ corrB, const unsigned short* __restrict__ wpk,
    unsigned short* __restrict__ y, float* __restrict__ P1, float* __restrict__ P2)
{
    int b = blockIdx.y, py0 = blockIdx.x << 1;
    int tid = threadIdx.x;
    int wave = tid >> 6, lane = tid & 63, q = lane >> 4, l15 = lane & 15;
    __shared__ short tile[16896];
    __shared__ float Ys[4][64], Ys2[4][64];

    {
        int row = tid >> 6, ic = tid & 63;
        int py = py0 - 1 + row;
        int rbase = (row * 66) << 6;
        int icblk = ic >> 3, icl = ic & 7;
        if (py >= 0 && py < 64) {
            const uint4* src = (const uint4*)(corrB + (((long)(b << 6) + ic) << 12) + (py << 6));
            #pragma unroll
            for (int c8 = 0; c8 < 8; ++c8) {
                uint4 u = src[c8];
                const unsigned short* us = (const unsigned short*)&u;
                #pragma unroll
                for (int e = 0; e < 8; ++e) {
                    int col = (c8 << 3) + e + 1;
                    int sw = icblk ^ (col & 7);
                    tile[rbase + (col << 6) + (sw << 3) + icl] = us[e];
                }
            }
        } else {
            for (int col = 1; col <= 64; ++col) {
                int sw = icblk ^ (col & 7);
                tile[rbase + (col << 6) + (sw << 3) + icl] = 0;
            }
        }
        tile[rbase + (icblk << 3) + icl] = 0;
        tile[rbase + (65 << 6) + (((icblk ^ 1) << 3)) + icl] = 0;
    }
    __syncthreads();

    floatx4 acc[2][4];
    #pragma unroll
    for (int i = 0; i < 2; ++i)
        #pragma unroll
        for (int ot = 0; ot < 4; ++ot) acc[i][ot] = (floatx4){0.f, 0.f, 0.f, 0.f};

    int pt0 = wave << 1;
    int rowb[2], colb[2];
    #pragma unroll
    for (int i = 0; i < 2; ++i) {
        int p = ((pt0 + i) << 4) + l15;
        rowb[i] = p >> 6;
        colb[i] = p & 63;
    }
    #pragma unroll
    for (int c = 0; c < 18; ++c) {
        const int tap = c >> 1, ky = tap / 3, kx = tap % 3, h = c & 1;
        short8 bfr[4], afr[2];
        #pragma unroll
        for (int ot = 0; ot < 4; ++ot)
            bfr[ot] = *(const short8*)(wpk + ((c << 6) + (ot << 4) + l15) * 32 + (q << 3));
        #pragma unroll
        for (int i = 0; i < 2; ++i) {
            int row = rowb[i] + ky, col = colb[i] + kx;
            int sw = ((h << 2) + q) ^ (col & 7);
            afr[i] = *(const short8*)&tile[((row * 66 + col) << 6) + (sw << 3)];
        }
        #pragma unroll
        for (int i = 0; i < 2; ++i)
            #pragma unroll
            for (int ot = 0; ot < 4; ++ot)
                acc[i][ot] = __builtin_amdgcn_mfma_f32_16x16x32_bf16(afr[i], bfr[ot], acc[i][ot], 0, 0, 0);
    }
    #pragma unroll
    for (int i = 0; i < 2; ++i) {
        #pragma unroll
        for (int r = 0; r < 4; ++r) {
            int p = ((pt0 + i) << 4) + (q << 2) + r;
            int py = py0 + (p >> 6), pxc = p & 63;
            int base = ((b << 12) + (py << 6) + pxc) << 6;
            #pragma unroll
            for (int ot = 0; ot < 4; ++ot)
                y[base + (ot << 4) + l15] = f2bf(acc[i][ot][r]);
        }
    }
    #pragma unroll
    for (int ot = 0; ot < 4; ++ot) {
        float s = 0.f, s2 = 0.f;
        #pragma unroll
        for (int i = 0; i < 2; ++i)
            #pragma unroll
            for (int r = 0; r < 4; ++r) { float v = acc[i][ot][r]; s += v; s2 += v * v; }
        s += __shfl_xor(s, 16, 64); s2 += __shfl_xor(s2, 16, 64);
        s += __shfl_xor(s, 32, 64); s2 += __shfl_xor(s2, 32, 64);
        if (lane < 16) { Ys[wave][(ot << 4) + lane] = s; Ys2[wave][(ot << 4) + lane] = s2; }
    }
    __syncthreads();
    if (tid < 64) {
        float s  = Ys[0][tid] + Ys[1][tid] + Ys[2][tid] + Ys[3][tid];
        float s2 = Ys2[0][tid] + Ys2[1][tid] + Ys2[2][tid] + Ys2[3][tid];
        int idx = (((b << 5) + blockIdx.x) << 6) + tid;
        P1[idx] = s; P2[idx] = s2;
    }
}

__global__ __launch_bounds__(256) void k6_nhwc(
    const unsigned short* __restrict__ y, const float* __restrict__ P1, const float* __restrict__ P2,
    const float* __restrict__ gnw, const float* __restrict__ gnb,
    const float* __restrict__ w2, const float* __restrict__ b2, float* __restrict__ out)
{
    int b = blockIdx.y;
    int px0 = blockIdx.x << 7;
    int tid = threadIdx.x, wave = tid >> 6, lane = tid & 63;
    __shared__ float sA[64], sB[64];
    if (tid < 64) {
        int c = tid;
        float s = 0.f, s2 = 0.f;
        for (int t = 0; t < 32; ++t) {
            int idx = (((b << 5) + t) << 6) + c;
            s += P1[idx]; s2 += P2[idx];
        }
        float sp = __shfl_xor(s, 1, 64), s2p = __shfl_xor(s2, 1, 64);
        float S = s + sp, S2 = s2 + s2p;
        float mean = S * (1.f / 8192.f);
        float var  = S2 * (1.f / 8192.f) - mean * mean;
        float inv  = rsqrtf(var + EPS);
        float a = gnw[c] * inv;
        sA[c] = a; sB[c] = gnb[c] - mean * a;
    }
    __syncthreads();
    int ocp = lane & 31, ph = lane >> 5;
    int c0 = 2 * ocp;
    float a0 = sA[c0],     b0 = sB[c0],     w20 = w2[c0];
    float a1 = sA[c0 + 1], b1 = sB[c0 + 1], w21 = w2[c0 + 1];
    float bias = b2[0];
    const unsigned* yp = (const unsigned*)y;
    for (int i = 0; i < 16; ++i) {
        int px = px0 + (i << 3) + (wave << 1) + ph;
        unsigned u = yp[(((b << 12) + px) << 5) + ocp];
        float f0 = bf2f((unsigned short)(u & 0xFFFF));
        float f1 = bf2f((unsigned short)(u >> 16));
        float v0 = a0 * f0 + b0; v0 = v0 > 0.f ? v0 : 0.f;
        float v1 = a1 * f1 + b1; v1 = v1 > 0.f ? v1 : 0.f;
        float val = w20 * v0 + w21 * v1;
        #pragma unroll
        for (int m = 16; m >= 1; m >>= 1) val += __shfl_xor(val, m, 64);
        if (ocp == 0) out[(b << 12) + px] = val + bias;
    }
}

extern "C" void kernel_launch(void* const* d_in, const int* in_sizes, int n_in,
                              void* d_out, int out_size, void* d_ws, size_t ws_size,
                              hipStream_t stream)
{
    float* ws = (float*)d_ws;

    Params prm;
    prm.tmpl   = (const float*)d_in[0];
    prm.search = (const float*)d_in[1];
    prm.w_t    = (const float*)d_in[2];
    prm.gn_t_w = (const float*)d_in[3];
    prm.gn_t_b = (const float*)d_in[4];
    prm.w_s    = (const float*)d_in[5];
    prm.gn_s_w = (const float*)d_in[6];
    prm.gn_s_b = (const float*)d_in[7];
    prm.w_p1   = (const float*)d_in[8];
    prm.gn_p_w = (const float*)d_in[9];
    prm.gn_p_b = (const float*)d_in[10];
    prm.w_p2   = (const float*)d_in[11];
    prm.b_p2   = (const float*)d_in[12];
    prm.out    = (float*)d_out;

    prm.TG = ws;                         // 2048
    prm.TK = ws + 2048;                  // 100352 -> ends 102400
    prm.P1 = ws + 102400;                // 65536 -> ends 167936
    prm.P2 = ws + 167936;                // 65536 -> ends 233472
    prm.WPK = (unsigned short*)(ws + 233472);     // 36864 bf16
    prm.SRAW = ws + 262144;                       // 8388608 floats (32 MB)
    prm.CORRB = (unsigned short*)(ws + 8650752);  // 4194304 bf16 (8 MB)
    // overlays (timeline-disjoint, separated by grid.sync / kernel boundaries):
    prm.WSB  = prm.CORRB;                         // written P0, read P1; overwritten P3
    prm.YRAW = (unsigned short*)prm.SRAW;         // written P4 (SRAW dead after P3)

    // --- co-residency-safe cooperative launch (static-cached occupancy query) ---
    static int NB = -1;
    if (NB < 0) {
        int perCU = 0;
        hipError_t e1 = hipOccupancyMaxActiveBlocksPerMultiprocessor(
            &perCU, (const void*)fused, 256, 0);
        hipDeviceProp_t props;
        hipError_t e2 = hipGetDeviceProperties(&props, 0);
        if (e1 == hipSuccess && e2 == hipSuccess && perCU >= 1) {
            long t = (long)perCU * (long)props.multiProcessorCount;
            NB = (int)(t < 1024 ? t : 1024);
            if (NB < 64) NB = 0;   // pathological — use fallback
        } else {
            NB = 0;                // query failed — use fallback
        }
    }

    hipError_t lerr = hipErrorUnknown;
    if (NB > 0) {
        void* args[] = { (void*)&prm };
        lerr = hipLaunchCooperativeKernel((const void*)fused, dim3(NB), dim3(256), args, 0, stream);
    }
    if (lerr != hipSuccess) {
        // fallback: round-4 split pipeline (known-pass)
        k_pack<<<208, 256, 0, stream>>>(prm.w_s, prm.WSB, prm.w_p1, prm.WPK);
        k1_template<<<256, 256, 0, stream>>>(prm.tmpl, prm.w_t, prm.gn_t_w, prm.gn_t_b, prm.TG, prm.TK);
        k2_mfma<<<dim3(32, 32), 256, 0, stream>>>(prm.search, prm.WSB, prm.SRAW, prm.P1, prm.P2);
        k4_corr<<<2048, 256, 0, stream>>>(prm.SRAW, prm.P1, prm.P2, prm.gn_s_w, prm.gn_s_b, prm.TG, prm.TK, prm.CORRB);
        k5_mfma<<<dim3(32, 32), 256, 0, stream>>>(prm.CORRB, prm.WPK, prm.YRAW, prm.P1, prm.P2);
        k6_nhwc<<<dim3(32, 32), 256, 0, stream>>>(prm.YRAW, prm.P1, prm.P2, prm.gn_p_w, prm.gn_p_b, prm.w_p2, prm.b_p2, prm.out);
    }
}

// Round 7
// 331.191 us; speedup vs baseline: 1.8673x; 1.8673x over previous
//
#include <hip/hip_runtime.h>

#define EPS 1e-5f

// B=32, C=256, CC=64, template 14x14, search 64x64, K=7, 32 groups (2ch/group)

typedef __attribute__((ext_vector_type(8))) short short8;
typedef __attribute__((ext_vector_type(4))) float floatx4;

__device__ __forceinline__ unsigned short f2bf(float x) {
    union { float f; unsigned u; } v; v.f = x;
    unsigned r = v.u + 0x7FFFu + ((v.u >> 16) & 1u);   // RNE
    return (unsigned short)(r >> 16);
}
__device__ __forceinline__ float bf2f(unsigned short h) {
    union { unsigned u; float f; } v; v.u = ((unsigned)h) << 16;
    return v.f;
}

// ---------------- K01: template path (blocks 0-255) + weight prepack (blocks 256-463) ----------------
__global__ __launch_bounds__(256) void k01_tmpl_pack(
    const float* __restrict__ tmpl, const float* __restrict__ w_t,
    const float* __restrict__ gnw, const float* __restrict__ gnb,
    float* __restrict__ t_global, float* __restrict__ t_kernel,
    const float* __restrict__ w_s, unsigned short* __restrict__ wsb,
    const float* __restrict__ w1, unsigned short* __restrict__ wpk)
{
    int tid = threadIdx.x;
    if (blockIdx.x >= 256) {
        int idx = ((blockIdx.x - 256) << 8) + tid;
        if (idx < 16384) {
            wsb[idx] = f2bf(w_s[idx]);
        } else if (idx < 53248) {
            int i = idx - 16384;
            int c = i >> 11, rem = i & 2047, oc = rem >> 5, k = rem & 31;
            int tap = c >> 1, ic = ((c & 1) << 5) + k;
            wpk[i] = f2bf(w1[oc * 576 + ic * 9 + tap]);
        }
        return;
    }
    int b = blockIdx.x >> 3, h = blockIdx.x & 7;   // h: eighth of oc (8 oc)
    __shared__ float Xs[32][200];   // 32-ic chunk x 196 px (pad 200)
    __shared__ float T0[8][200];
    __shared__ float sums[8], sumsq[8], Ac[8], Bb[8];
    float acc[8];
    #pragma unroll
    for (int o = 0; o < 8; ++o) acc[o] = 0.f;
    const float* wb = w_t + (h * 8) * 256;         // uniform -> s_load
    const float* tb = tmpl + b * 50176;
    int p = tid;
    for (int chunk = 0; chunk < 8; ++chunk) {
        __syncthreads();
        #pragma unroll
        for (int j = 0; j < 7; ++j) {
            int f4 = tid + (j << 8);
            if (f4 < 1568) {                        // 32 rows x 49 float4
                int ic = f4 / 49, px4 = (f4 - ic * 49) << 2;
                float4 v = *(const float4*)(tb + (chunk * 32 + ic) * 196 + px4);
                *(float4*)&Xs[ic][px4] = v;
            }
        }
        __syncthreads();
        if (p < 196) {
            for (int cc = 0; cc < 32; ++cc) {
                float xv = Xs[cc][p];
                #pragma unroll
                for (int o = 0; o < 8; ++o)
                    acc[o] += xv * wb[o * 256 + chunk * 32 + cc];
            }
        }
    }
    __syncthreads();
    if (p < 196) {
        #pragma unroll
        for (int o = 0; o < 8; ++o) T0[o][p] = acc[o];
    }
    __syncthreads();
    if (tid < 128) {   // 16 lanes per channel
        int c = tid >> 4, part = tid & 15;
        float s = 0.f, s2 = 0.f;
        for (int qq = part; qq < 196; qq += 16) { float v = T0[c][qq]; s += v; s2 += v * v; }
        #pragma unroll
        for (int off = 1; off < 16; off <<= 1) {
            s += __shfl_xor(s, off, 16); s2 += __shfl_xor(s2, off, 16);
        }
        if (part == 0) { sums[c] = s; sumsq[c] = s2; }
    }
    __syncthreads();
    if (tid < 4) {   // group = channel pair, both in this block
        float S  = sums[2 * tid] + sums[2 * tid + 1];
        float S2 = sumsq[2 * tid] + sumsq[2 * tid + 1];
        float mean = S * (1.f / 392.f);
        float var  = S2 * (1.f / 392.f) - mean * mean;
        float inv  = rsqrtf(var + EPS);
        for (int e = 0; e < 2; ++e) {
            int c = 2 * tid + e, gc = h * 8 + c;
            float a = gnw[gc] * inv;
            Ac[c] = a; Bb[c] = gnb[gc] - mean * a;
        }
    }
    __syncthreads();
    if (p < 196) {
        #pragma unroll
        for (int o = 0; o < 8; ++o) {
            float v = Ac[o] * T0[o][p] + Bb[o];
            T0[o][p] = v > 0.f ? v : 0.f;
        }
    }
    __syncthreads();
    if (tid < 128) {
        int c = tid >> 4, part = tid & 15, gc = h * 8 + c;
        float s = 0.f;
        for (int qq = part; qq < 196; qq += 16) s += T0[c][qq];
        #pragma unroll
        for (int off = 1; off < 16; off <<= 1) s += __shfl_xor(s, off, 16);
        if (part == 0) t_global[b * 64 + gc] = s * (1.f / 196.f);
        for (int t = part; t < 49; t += 16) {
            int ky = t / 7, kx = t - 7 * ky;
            float v = T0[c][(2 * ky) * 14 + 2 * kx]     + T0[c][(2 * ky) * 14 + 2 * kx + 1]
                    + T0[c][(2 * ky + 1) * 14 + 2 * kx] + T0[c][(2 * ky + 1) * 14 + 2 * kx + 1];
            t_kernel[(b * 64 + gc) * 49 + t] = v * 0.25f;
        }
    }
}

// ---------------- K2: search conv1x1 via bf16 MFMA, 128-px tiles, double-buffered LDS ----------------
// grid (32 px-tiles, 32 b). Block 256 thr (4 waves): 128 px x 64 oc, K=256.
// One __syncthreads per K-chunk; next-chunk global loads issued before MFMA of current.
__global__ __launch_bounds__(256) void k2_mfma(
    const float* __restrict__ x, const unsigned short* __restrict__ wsb,
    float* __restrict__ sraw, float* __restrict__ P1, float* __restrict__ P2)
{
    int b = blockIdx.y, p0 = blockIdx.x << 7;
    int tid = threadIdx.x;
    int wave = tid >> 6, lane = tid & 63, q = lane >> 4, l15 = lane & 15;
    __shared__ short tile[2][128 * 64];   // [px 128][ic 64] bf16, icblk xor-swizzled by px&7
    __shared__ float Ps[4][64], Ps2[4][64];

    floatx4 acc[2][4];
    #pragma unroll
    for (int i = 0; i < 2; ++i)
        #pragma unroll
        for (int mt = 0; mt < 4; ++mt) acc[i][mt] = (floatx4){0.f, 0.f, 0.f, 0.f};

    int pxq = (tid & 31) << 2;     // px base (4 consecutive px per thread)
    int icr = tid >> 5;            // ic group 0..7 (8 consecutive ic per thread)
    const float* xb = x + ((long)b << 20) + p0 + pxq;
    float4 L[8];
    #pragma unroll
    for (int i = 0; i < 8; ++i)
        L[i] = *(const float4*)(xb + ((long)((icr << 3) + i) << 12));
    // stage chunk 0 into buf 0
    #pragma unroll
    for (int j = 0; j < 4; ++j) {
        int px = pxq + j;
        short8 s8;
        #pragma unroll
        for (int e = 0; e < 8; ++e) s8[e] = (short)f2bf(((const float*)&L[e])[j]);
        int sw = icr ^ (px & 7);
        *(short8*)&tile[0][(px << 6) + (sw << 3)] = s8;
    }
    #pragma unroll
    for (int chunk = 0; chunk < 4; ++chunk) {           // 64 ic per chunk
        const int cur = chunk & 1;
        __syncthreads();   // buf[cur] staged; prior reads of buf[cur^1] done
        if (chunk < 3) {   // issue next chunk's loads; drain under MFMA below
            #pragma unroll
            for (int i = 0; i < 8; ++i)
                L[i] = *(const float4*)(xb + ((long)(((chunk + 1) << 6) + (icr << 3) + i) << 12));
        }
        #pragma unroll
        for (int kq = 0; kq < 2; ++kq) {                // 32-ic MFMA chunks
            short8 afr[4], bfr[2];
            int kbase = (chunk << 6) + (kq << 5) + (q << 3);
            #pragma unroll
            for (int mt = 0; mt < 4; ++mt)
                afr[mt] = *(const short8*)(wsb + ((mt << 4) + l15) * 256 + kbase);
            #pragma unroll
            for (int i = 0; i < 2; ++i) {
                int px = (((wave << 1) + i) << 4) + l15;
                int sw = ((kq << 2) + q) ^ (px & 7);
                bfr[i] = *(const short8*)&tile[cur][(px << 6) + (sw << 3)];
            }
            #pragma unroll
            for (int i = 0; i < 2; ++i)
                #pragma unroll
                for (int mt = 0; mt < 4; ++mt)
                    acc[i][mt] = __builtin_amdgcn_mfma_f32_16x16x32_bf16(afr[mt], bfr[i], acc[i][mt], 0, 0, 0);
        }
        if (chunk < 3) {   // stage next chunk into the other buffer (safe: post-sync)
            #pragma unroll
            for (int j = 0; j < 4; ++j) {
                int px = pxq + j;
                short8 s8;
                #pragma unroll
                for (int e = 0; e < 8; ++e) s8[e] = (short)f2bf(((const float*)&L[e])[j]);
                int sw = icr ^ (px & 7);
                *(short8*)&tile[cur ^ 1][(px << 6) + (sw << 3)] = s8;
            }
        }
    }
    // D: col(lane&15)=px-in-frag, row(q*4+r)=oc-in-tile
    float* ob = sraw + ((long)b << 18) + p0;
    #pragma unroll
    for (int i = 0; i < 2; ++i) {
        int pxb = ((wave << 1) + i) << 4;
        #pragma unroll
        for (int mt = 0; mt < 4; ++mt)
            #pragma unroll
            for (int r = 0; r < 4; ++r) {
                int oc = (mt << 4) + (q << 2) + r;
                ob[(oc << 12) + pxb + l15] = acc[i][mt][r];
            }
    }
    // fused GN stat partials
    #pragma unroll
    for (int mt = 0; mt < 4; ++mt) {
        #pragma unroll
        for (int r = 0; r < 4; ++r) {
            float s = 0.f, s2 = 0.f;
            #pragma unroll
            for (int i = 0; i < 2; ++i) { float v = acc[i][mt][r]; s += v; s2 += v * v; }
            #pragma unroll
            for (int off = 1; off < 16; off <<= 1) {
                s  += __shfl_xor(s, off, 64);
                s2 += __shfl_xor(s2, off, 64);
            }
            if (l15 == 0) {
                int oc = (mt << 4) + (q << 2) + r;
                Ps[wave][oc] = s; Ps2[wave][oc] = s2;
            }
        }
    }
    __syncthreads();
    if (tid < 64) {
        float s  = Ps[0][tid] + Ps[1][tid] + Ps[2][tid] + Ps[3][tid];
        float s2 = Ps2[0][tid] + Ps2[1][tid] + Ps2[2][tid] + Ps2[3][tid];
        int idx = (((b << 5) + blockIdx.x) << 6) + tid;
        P1[idx] = s; P2[idx] = s2;
    }
}

// ---------------- K4: corr = s*t_global + depthwise7x7 -> bf16 NCHW (inline s-GN finalize) ----------------
__global__ __launch_bounds__(256) void k4_corr(
    const float* __restrict__ sraw, const float* __restrict__ P1, const float* __restrict__ P2,
    const float* __restrict__ gnw, const float* __restrict__ gnb,
    const float* __restrict__ t_global, const float* __restrict__ t_kernel,
    unsigned short* __restrict__ corr)
{
    int bc = blockIdx.x;
    int b = bc >> 6, c = bc & 63;
    int tid = threadIdx.x;
    __shared__ float t4[70 * 70];
    __shared__ float ker[49];
    __shared__ float fin4[4];
    __shared__ float sAB[2];
    if (tid < 32) {   // finalize this block's GN coefs from 32 tile-partials x 2 channels
        int ch = (c & ~1) + (tid >> 4), k = tid & 15;
        int base = ((b << 5) + k) << 6;
        float s  = P1[base + ch] + P1[base + (16 << 6) + ch];
        float s2 = P2[base + ch] + P2[base + (16 << 6) + ch];
        #pragma unroll
        for (int off = 1; off < 16; off <<= 1) {
            s += __shfl_xor(s, off, 16); s2 += __shfl_xor(s2, off, 16);
        }
        if (k == 0) { fin4[tid >> 4] = s; fin4[2 + (tid >> 4)] = s2; }
    }
    // zero only the 3-wide halo (interior is fully overwritten below)
    for (int i = tid; i < 804; i += 256) {
        if (i < 420) {                       // top 3 + bottom 3 full-width rows
            int r = i / 70, cc = i - 70 * r;
            int row = (r < 3) ? r : (r + 64);
            t4[row * 70 + cc] = 0.f;
        } else {                             // left 3 + right 3 cols of rows 3..66
            int j = i - 420;
            int r = (j / 6) + 3, e = j - 6 * ((r - 3));
            int col = (e < 3) ? e : (e + 64);
            t4[r * 70 + col] = 0.f;
        }
    }
    if (tid < 49) ker[tid] = t_kernel[bc * 49 + tid];
    __syncthreads();
    if (tid == 0) {
        float S = fin4[0] + fin4[1], S2 = fin4[2] + fin4[3];
        float mean = S * (1.f / 8192.f);
        float var  = S2 * (1.f / 8192.f) - mean * mean;
        float inv  = rsqrtf(var + EPS);
        float a = gnw[c] * inv;
        sAB[0] = a; sAB[1] = gnb[c] - mean * a;
    }
    __syncthreads();
    float a = sAB[0], bb = sAB[1], tg = t_global[bc];
    const float4* sb4 = (const float4*)(sraw + ((long)bc << 12));
    for (int i4 = tid; i4 < 1024; i4 += 256) {
        float4 v4 = sb4[i4];
        int y = i4 >> 4, xx = (i4 & 15) << 2;
        float* dst = &t4[(y + 3) * 70 + xx + 3];
        float v;
        v = a * v4.x + bb; dst[0] = v > 0.f ? v : 0.f;
        v = a * v4.y + bb; dst[1] = v > 0.f ? v : 0.f;
        v = a * v4.z + bb; dst[2] = v > 0.f ? v : 0.f;
        v = a * v4.w + bb; dst[3] = v > 0.f ? v : 0.f;
    }
    __syncthreads();
    int x = tid & 63, ys = (tid >> 6) << 4;
    float acc[16];
    #pragma unroll
    for (int j = 0; j < 16; ++j) acc[j] = 0.f;
    #pragma unroll
    for (int kx = 0; kx < 7; ++kx) {
        float col[22];
        #pragma unroll
        for (int j = 0; j < 22; ++j) col[j] = t4[(ys + j) * 70 + x + kx];
        #pragma unroll
        for (int ky = 0; ky < 7; ++ky) {
            float kv = ker[ky * 7 + kx];
            #pragma unroll
            for (int j = 0; j < 16; ++j) acc[j] += kv * col[j + ky];
        }
    }
    unsigned short* ob = corr + ((long)bc << 12);
    #pragma unroll
    for (int j = 0; j < 16; ++j) {
        float sval = t4[(ys + j + 3) * 70 + x + 3];
        ob[((ys + j) << 6) + x] = f2bf(acc[j] + sval * tg);
    }
}

// ---------------- K5: conv3x3 via bf16 MFMA, reads NCHW bf16 corr directly ----------------
__global__ __launch_bounds__(256) void k5_mfma(
    const unsigned short* __restrict__ corrB, const unsigned short* __restrict__ wpk,
    unsigned short* __restrict__ y, float* __restrict__ P1, float* __restrict__ P2)
{
    int b = blockIdx.y, py0 = blockIdx.x << 1;
    int tid = threadIdx.x;
    int wave = tid >> 6, lane = tid & 63, q = lane >> 4, l15 = lane & 15;
    __shared__ short tile[16896];   // [row 4][col 66][ic 64] bf16, xor-swizzled (33792 B)
    __shared__ float Ys[4][64], Ys2[4][64];

    {
        int row = tid >> 6, ic = tid & 63;   // wave = one tile row, lane = ic
        int py = py0 - 1 + row;
        int rbase = (row * 66) << 6;
        int icblk = ic >> 3, icl = ic & 7;
        if (py >= 0 && py < 64) {
            const uint4* src = (const uint4*)(corrB + (((long)(b << 6) + ic) << 12) + (py << 6));
            #pragma unroll
            for (int c8 = 0; c8 < 8; ++c8) {
                uint4 u = src[c8];
                const unsigned short* us = (const unsigned short*)&u;
                #pragma unroll
                for (int e = 0; e < 8; ++e) {
                    int col = (c8 << 3) + e + 1;
                    int sw = icblk ^ (col & 7);
                    tile[rbase + (col << 6) + (sw << 3) + icl] = us[e];
                }
            }
        } else {
            for (int col = 1; col <= 64; ++col) {
                int sw = icblk ^ (col & 7);
                tile[rbase + (col << 6) + (sw << 3) + icl] = 0;
            }
        }
        // halo cols 0 (px=-1) and 65 (px=64) are always out of image -> zero
        tile[rbase + (icblk << 3) + icl] = 0;
        tile[rbase + (65 << 6) + (((icblk ^ 1) << 3)) + icl] = 0;
    }
    __syncthreads();

    floatx4 acc[2][4];
    #pragma unroll
    for (int i = 0; i < 2; ++i)
        #pragma unroll
        for (int ot = 0; ot < 4; ++ot) acc[i][ot] = (floatx4){0.f, 0.f, 0.f, 0.f};

    int pt0 = wave << 1;
    int rowb[2], colb[2];
    #pragma unroll
    for (int i = 0; i < 2; ++i) {
        int p = ((pt0 + i) << 4) + l15;
        rowb[i] = p >> 6;
        colb[i] = p & 63;
    }
    #pragma unroll
    for (int c = 0; c < 18; ++c) {
        const int tap = c >> 1, ky = tap / 3, kx = tap % 3, h = c & 1;
        short8 bfr[4], afr[2];
        #pragma unroll
        for (int ot = 0; ot < 4; ++ot)
            bfr[ot] = *(const short8*)(wpk + ((c << 6) + (ot << 4) + l15) * 32 + (q << 3));
        #pragma unroll
        for (int i = 0; i < 2; ++i) {
            int row = rowb[i] + ky, col = colb[i] + kx;
            int sw = ((h << 2) + q) ^ (col & 7);
            afr[i] = *(const short8*)&tile[((row * 66 + col) << 6) + (sw << 3)];
        }
        #pragma unroll
        for (int i = 0; i < 2; ++i)
            #pragma unroll
            for (int ot = 0; ot < 4; ++ot)
                acc[i][ot] = __builtin_amdgcn_mfma_f32_16x16x32_bf16(afr[i], bfr[ot], acc[i][ot], 0, 0, 0);
    }
    #pragma unroll
    for (int i = 0; i < 2; ++i) {
        #pragma unroll
        for (int r = 0; r < 4; ++r) {
            int p = ((pt0 + i) << 4) + (q << 2) + r;
            int py = py0 + (p >> 6), pxc = p & 63;
            int base = ((b << 12) + (py << 6) + pxc) << 6;
            #pragma unroll
            for (int ot = 0; ot < 4; ++ot)
                y[base + (ot << 4) + l15] = f2bf(acc[i][ot][r]);
        }
    }
    // fused GN stat partials: lane holds oc = ot*16 + l15
    #pragma unroll
    for (int ot = 0; ot < 4; ++ot) {
        float s = 0.f, s2 = 0.f;
        #pragma unroll
        for (int i = 0; i < 2; ++i)
            #pragma unroll
            for (int r = 0; r < 4; ++r) { float v = acc[i][ot][r]; s += v; s2 += v * v; }
        s += __shfl_xor(s, 16, 64); s2 += __shfl_xor(s2, 16, 64);
        s += __shfl_xor(s, 32, 64); s2 += __shfl_xor(s2, 32, 64);
        if (lane < 16) { Ys[wave][(ot << 4) + lane] = s; Ys2[wave][(ot << 4) + lane] = s2; }
    }
    __syncthreads();
    if (tid < 64) {
        float s  = Ys[0][tid] + Ys[1][tid] + Ys[2][tid] + Ys[3][tid];
        float s2 = Ys2[0][tid] + Ys2[1][tid] + Ys2[2][tid] + Ys2[3][tid];
        int idx = (((b << 5) + blockIdx.x) << 6) + tid;
        P1[idx] = s; P2[idx] = s2;
    }
}

// ---------------- K6: epilogue on NHWC bf16 y (inline y-GN finalize) ----------------
__global__ __launch_bounds__(256) void k6_nhwc(
    const unsigned short* __restrict__ y, const float* __restrict__ P1, const float* __restrict__ P2,
    const float* __restrict__ gnw, const float* __restrict__ gnb,
    const float* __restrict__ w2, const float* __restrict__ b2, float* __restrict__ out)
{
    int b = blockIdx.y;
    int px0 = blockIdx.x << 7;
    int tid = threadIdx.x, wave = tid >> 6, lane = tid & 63;
    __shared__ float sA[64], sB[64];
    if (tid < 64) {
        int c = tid;
        float s = 0.f, s2 = 0.f;
        for (int t = 0; t < 32; ++t) {
            int idx = (((b << 5) + t) << 6) + c;
            s += P1[idx]; s2 += P2[idx];
        }
        float sp = __shfl_xor(s, 1, 64), s2p = __shfl_xor(s2, 1, 64);
        float S = s + sp, S2 = s2 + s2p;
        float mean = S * (1.f / 8192.f);
        float var  = S2 * (1.f / 8192.f) - mean * mean;
        float inv  = rsqrtf(var + EPS);
        float a = gnw[c] * inv;
        sA[c] = a; sB[c] = gnb[c] - mean * a;
    }
    __syncthreads();
    int ocp = lane & 31, ph = lane >> 5;
    int c0 = 2 * ocp;
    float a0 = sA[c0],     b0 = sB[c0],     w20 = w2[c0];
    float a1 = sA[c0 + 1], b1 = sB[c0 + 1], w21 = w2[c0 + 1];
    float bias = b2[0];
    const unsigned* yp = (const unsigned*)y;
    for (int i = 0; i < 16; ++i) {
        int px = px0 + (i << 3) + (wave << 1) + ph;
        unsigned u = yp[(((b << 12) + px) << 5) + ocp];
        float f0 = bf2f((unsigned short)(u & 0xFFFF));
        float f1 = bf2f((unsigned short)(u >> 16));
        float v0 = a0 * f0 + b0; v0 = v0 > 0.f ? v0 : 0.f;
        float v1 = a1 * f1 + b1; v1 = v1 > 0.f ? v1 : 0.f;
        float val = w20 * v0 + w21 * v1;
        #pragma unroll
        for (int m = 16; m >= 1; m >>= 1) val += __shfl_xor(val, m, 64);
        if (ocp == 0) out[(b << 12) + px] = val + bias;
    }
}

extern "C" void kernel_launch(void* const* d_in, const int* in_sizes, int n_in,
                              void* d_out, int out_size, void* d_ws, size_t ws_size,
                              hipStream_t stream)
{
    const float* tmpl   = (const float*)d_in[0];
    const float* search = (const float*)d_in[1];
    const float* w_t    = (const float*)d_in[2];
    const float* gn_t_w = (const float*)d_in[3];
    const float* gn_t_b = (const float*)d_in[4];
    const float* w_s    = (const float*)d_in[5];
    const float* gn_s_w = (const float*)d_in[6];
    const float* gn_s_b = (const float*)d_in[7];
    const float* w_p1   = (const float*)d_in[8];
    const float* gn_p_w = (const float*)d_in[9];
    const float* gn_p_b = (const float*)d_in[10];
    const float* w_p2   = (const float*)d_in[11];
    const float* b_p2   = (const float*)d_in[12];
    float* out = (float*)d_out;
    float* ws  = (float*)d_ws;

    float* TG   = ws;                    // 2048
    float* TK   = ws + 2048;             // 100352 -> ends 102400
    float* P1   = ws + 102400;           // 65536 (32b x 32 tiles x 64 oc) -> ends 167936
    float* P2   = ws + 167936;           // 65536 -> ends 233472
    unsigned short* WPK = (unsigned short*)(ws + 233472);   // 36864 bf16 -> ends 251904
    float* SRAW = ws + 262144;           // 8388608 floats (32 MB) -> ends 8650752
    unsigned short* CORRB = (unsigned short*)(ws + 8650752); // 4194304 bf16 (8 MB)
    // overlays (timeline-disjoint):
    unsigned short* WSB   = (unsigned short*)CORRB;          // k01 writes, k2 reads; k4 overwrites
    unsigned short* YRAW  = (unsigned short*)SRAW;           // k5 writes after SRAW dead (k4 last reader)

    k01_tmpl_pack<<<464, 256, 0, stream>>>(tmpl, w_t, gn_t_w, gn_t_b, TG, TK, w_s, WSB, w_p1, WPK);
    k2_mfma<<<dim3(32, 32), 256, 0, stream>>>(search, WSB, SRAW, P1, P2);
    k4_corr<<<2048, 256, 0, stream>>>(SRAW, P1, P2, gn_s_w, gn_s_b, TG, TK, CORRB);
    k5_mfma<<<dim3(32, 32), 256, 0, stream>>>(CORRB, WPK, YRAW, P1, P2);
    k6_nhwc<<<dim3(32, 32), 256, 0, stream>>>(YRAW, P1, P2, gn_p_w, gn_p_b, w_p2, b_p2, out);
}

// Round 9
// 305.807 us; speedup vs baseline: 2.0223x; 1.0830x over previous
//
#include <hip/hip_runtime.h>

#define EPS 1e-5f

// B=32, C=256, CC=64, template 14x14, search 64x64, K=7, 32 groups (2ch/group)

typedef __attribute__((ext_vector_type(8))) short short8;
typedef __attribute__((ext_vector_type(4))) float floatx4;

__device__ __forceinline__ unsigned short f2bf(float x) {
    union { float f; unsigned u; } v; v.f = x;
    unsigned r = v.u + 0x7FFFu + ((v.u >> 16) & 1u);   // RNE
    return (unsigned short)(r >> 16);
}
__device__ __forceinline__ float bf2f(unsigned short h) {
    union { unsigned u; float f; } v; v.u = ((unsigned)h) << 16;
    return v.f;
}

// ---------------- K_PACK: w_s and w_p1 fp32 -> bf16 prepack ----------------
__global__ __launch_bounds__(256) void k_pack(
    const float* __restrict__ w_s, unsigned short* __restrict__ wsb,
    const float* __restrict__ w1, unsigned short* __restrict__ wpk)
{
    int blk = blockIdx.x;
    if (blk < 64) {
        int i = blk * 256 + threadIdx.x;
        wsb[i] = f2bf(w_s[i]);
    } else {
        int i = (blk - 64) * 256 + threadIdx.x;
        if (i < 36864) {
            int c = i >> 11;
            int rem = i & 2047;
            int oc = rem >> 5;
            int k = rem & 31;
            int tap = c >> 1;
            int ic = ((c & 1) << 5) + k;
            wpk[i] = f2bf(w1[oc * 576 + ic * 9 + tap]);
        }
    }
}

// ---------------- K2X: template path (blocks 0-255) hidden under search conv1x1 MFMA (blocks 256-1279) ----------------
// Template outputs (TG/TK) are first consumed by k4, so template work overlaps k2's streaming.
// MFMA part: 128 px x 64 oc per block, K=256, double-buffered LDS, fused GN stat partials.
__global__ __launch_bounds__(256) void k2x(
    const float* __restrict__ x, const unsigned short* __restrict__ wsb,
    float* __restrict__ sraw, float* __restrict__ P1, float* __restrict__ P2,
    const float* __restrict__ tmpl, const float* __restrict__ w_t,
    const float* __restrict__ gnw, const float* __restrict__ gnb,
    float* __restrict__ t_global, float* __restrict__ t_kernel)
{
    int tid = threadIdx.x;
    __shared__ __align__(16) char smem[34816];

    if (blockIdx.x < 256) {
        // ======== template path: conv1x1(14x14) + GN + ReLU + pooled outputs ========
        int b = blockIdx.x >> 3, h = blockIdx.x & 7;   // h: eighth of oc (8 oc)
        float (*Xs)[200] = (float(*)[200])smem;              // 25600 B
        float (*T0)[200] = (float(*)[200])(smem + 25600);    // 6400 B -> ends 32000
        float* sums  = (float*)(smem + 32000);
        float* sumsq = (float*)(smem + 32032);
        float* Ac    = (float*)(smem + 32064);
        float* Bb    = (float*)(smem + 32096);
        float acc[8];
        #pragma unroll
        for (int o = 0; o < 8; ++o) acc[o] = 0.f;
        const float* wb = w_t + (h * 8) * 256;         // uniform -> s_load
        const float* tb = tmpl + b * 50176;
        int p = tid;
        for (int chunk = 0; chunk < 8; ++chunk) {
            __syncthreads();
            #pragma unroll
            for (int j = 0; j < 7; ++j) {
                int f4 = tid + (j << 8);
                if (f4 < 1568) {                        // 32 rows x 49 float4
                    int ic = f4 / 49, px4 = (f4 - ic * 49) << 2;
                    float4 v = *(const float4*)(tb + (chunk * 32 + ic) * 196 + px4);
                    *(float4*)&Xs[ic][px4] = v;
                }
            }
            __syncthreads();
            if (p < 196) {
                for (int cc = 0; cc < 32; ++cc) {
                    float xv = Xs[cc][p];
                    #pragma unroll
                    for (int o = 0; o < 8; ++o)
                        acc[o] += xv * wb[o * 256 + chunk * 32 + cc];
                }
            }
        }
        __syncthreads();
        if (p < 196) {
            #pragma unroll
            for (int o = 0; o < 8; ++o) T0[o][p] = acc[o];
        }
        __syncthreads();
        if (tid < 128) {   // 16 lanes per channel
            int c = tid >> 4, part = tid & 15;
            float s = 0.f, s2 = 0.f;
            for (int qq = part; qq < 196; qq += 16) { float v = T0[c][qq]; s += v; s2 += v * v; }
            #pragma unroll
            for (int off = 1; off < 16; off <<= 1) {
                s += __shfl_xor(s, off, 16); s2 += __shfl_xor(s2, off, 16);
            }
            if (part == 0) { sums[c] = s; sumsq[c] = s2; }
        }
        __syncthreads();
        if (tid < 4) {   // group = channel pair, both in this block
            float S  = sums[2 * tid] + sums[2 * tid + 1];
            float S2 = sumsq[2 * tid] + sumsq[2 * tid + 1];
            float mean = S * (1.f / 392.f);
            float var  = S2 * (1.f / 392.f) - mean * mean;
            float inv  = rsqrtf(var + EPS);
            for (int e = 0; e < 2; ++e) {
                int c = 2 * tid + e, gc = h * 8 + c;
                float a = gnw[gc] * inv;
                Ac[c] = a; Bb[c] = gnb[gc] - mean * a;
            }
        }
        __syncthreads();
        if (p < 196) {
            #pragma unroll
            for (int o = 0; o < 8; ++o) {
                float v = Ac[o] * T0[o][p] + Bb[o];
                T0[o][p] = v > 0.f ? v : 0.f;
            }
        }
        __syncthreads();
        if (tid < 128) {
            int c = tid >> 4, part = tid & 15, gc = h * 8 + c;
            float s = 0.f;
            for (int qq = part; qq < 196; qq += 16) s += T0[c][qq];
            #pragma unroll
            for (int off = 1; off < 16; off <<= 1) s += __shfl_xor(s, off, 16);
            if (part == 0) t_global[b * 64 + gc] = s * (1.f / 196.f);
            for (int t = part; t < 49; t += 16) {
                int ky = t / 7, kx = t - 7 * ky;
                float v = T0[c][(2 * ky) * 14 + 2 * kx]     + T0[c][(2 * ky) * 14 + 2 * kx + 1]
                        + T0[c][(2 * ky + 1) * 14 + 2 * kx] + T0[c][(2 * ky + 1) * 14 + 2 * kx + 1];
                t_kernel[(b * 64 + gc) * 49 + t] = v * 0.25f;
            }
        }
        return;
    }

    // ======== search conv1x1 MFMA ========
    int mblk = blockIdx.x - 256;
    int b = mblk >> 5, p0 = (mblk & 31) << 7;
    int wave = tid >> 6, lane = tid & 63, q = lane >> 4, l15 = lane & 15;
    short (*tile)[128 * 64] = (short(*)[128 * 64])smem;     // 2 x 16384 B
    float (*Ps)[64]  = (float(*)[64])(smem + 32768);        // 1024 B
    float (*Ps2)[64] = (float(*)[64])(smem + 33792);        // 1024 B -> ends 34816

    floatx4 acc[2][4];
    #pragma unroll
    for (int i = 0; i < 2; ++i)
        #pragma unroll
        for (int mt = 0; mt < 4; ++mt) acc[i][mt] = (floatx4){0.f, 0.f, 0.f, 0.f};

    int pxq = (tid & 31) << 2;     // px base (4 consecutive px per thread)
    int icr = tid >> 5;            // ic group 0..7 (8 consecutive ic per thread)
    const float* xb = x + ((long)b << 20) + p0 + pxq;
    float4 L[8];
    #pragma unroll
    for (int i = 0; i < 8; ++i)
        L[i] = *(const float4*)(xb + ((long)((icr << 3) + i) << 12));
    // stage chunk 0 into buf 0
    #pragma unroll
    for (int j = 0; j < 4; ++j) {
        int px = pxq + j;
        short8 s8;
        #pragma unroll
        for (int e = 0; e < 8; ++e) s8[e] = (short)f2bf(((const float*)&L[e])[j]);
        int sw = icr ^ (px & 7);
        *(short8*)&tile[0][(px << 6) + (sw << 3)] = s8;
    }
    #pragma unroll
    for (int chunk = 0; chunk < 4; ++chunk) {           // 64 ic per chunk
        const int cur = chunk & 1;
        __syncthreads();   // buf[cur] staged; prior reads of buf[cur^1] done
        if (chunk < 3) {   // issue next chunk's loads; drain under MFMA below
            #pragma unroll
            for (int i = 0; i < 8; ++i)
                L[i] = *(const float4*)(xb + ((long)(((chunk + 1) << 6) + (icr << 3) + i) << 12));
        }
        #pragma unroll
        for (int kq = 0; kq < 2; ++kq) {                // 32-ic MFMA chunks
            short8 afr[4], bfr[2];
            int kbase = (chunk << 6) + (kq << 5) + (q << 3);
            #pragma unroll
            for (int mt = 0; mt < 4; ++mt)
                afr[mt] = *(const short8*)(wsb + ((mt << 4) + l15) * 256 + kbase);
            #pragma unroll
            for (int i = 0; i < 2; ++i) {
                int px = (((wave << 1) + i) << 4) + l15;
                int sw = ((kq << 2) + q) ^ (px & 7);
                bfr[i] = *(const short8*)&tile[cur][(px << 6) + (sw << 3)];
            }
            #pragma unroll
            for (int i = 0; i < 2; ++i)
                #pragma unroll
                for (int mt = 0; mt < 4; ++mt)
                    acc[i][mt] = __builtin_amdgcn_mfma_f32_16x16x32_bf16(afr[mt], bfr[i], acc[i][mt], 0, 0, 0);
        }
        if (chunk < 3) {   // stage next chunk into the other buffer (safe: post-sync)
            #pragma unroll
            for (int j = 0; j < 4; ++j) {
                int px = pxq + j;
                short8 s8;
                #pragma unroll
                for (int e = 0; e < 8; ++e) s8[e] = (short)f2bf(((const float*)&L[e])[j]);
                int sw = icr ^ (px & 7);
                *(short8*)&tile[cur ^ 1][(px << 6) + (sw << 3)] = s8;
            }
        }
    }
    // D: col(lane&15)=px-in-frag, row(q*4+r)=oc-in-tile
    float* ob = sraw + ((long)b << 18) + p0;
    #pragma unroll
    for (int i = 0; i < 2; ++i) {
        int pxb = ((wave << 1) + i) << 4;
        #pragma unroll
        for (int mt = 0; mt < 4; ++mt)
            #pragma unroll
            for (int r = 0; r < 4; ++r) {
                int oc = (mt << 4) + (q << 2) + r;
                ob[(oc << 12) + pxb + l15] = acc[i][mt][r];
            }
    }
    // fused GN stat partials
    #pragma unroll
    for (int mt = 0; mt < 4; ++mt) {
        #pragma unroll
        for (int r = 0; r < 4; ++r) {
            float s = 0.f, s2 = 0.f;
            #pragma unroll
            for (int i = 0; i < 2; ++i) { float v = acc[i][mt][r]; s += v; s2 += v * v; }
            #pragma unroll
            for (int off = 1; off < 16; off <<= 1) {
                s  += __shfl_xor(s, off, 64);
                s2 += __shfl_xor(s2, off, 64);
            }
            if (l15 == 0) {
                int oc = (mt << 4) + (q << 2) + r;
                Ps[wave][oc] = s; Ps2[wave][oc] = s2;
            }
        }
    }
    __syncthreads();
    if (tid < 64) {
        float s  = Ps[0][tid] + Ps[1][tid] + Ps[2][tid] + Ps[3][tid];
        float s2 = Ps2[0][tid] + Ps2[1][tid] + Ps2[2][tid] + Ps2[3][tid];
        int idx = (((b << 5) + (mblk & 31)) << 6) + tid;
        P1[idx] = s; P2[idx] = s2;
    }
}

// ---------------- K4: corr = s*t_global + depthwise7x7 -> bf16 NCHW (inline s-GN finalize) ----------------
__global__ __launch_bounds__(256) void k4_corr(
    const float* __restrict__ sraw, const float* __restrict__ P1, const float* __restrict__ P2,
    const float* __restrict__ gnw, const float* __restrict__ gnb,
    const float* __restrict__ t_global, const float* __restrict__ t_kernel,
    unsigned short* __restrict__ corr)
{
    int bc = blockIdx.x;
    int b = bc >> 6, c = bc & 63;
    int tid = threadIdx.x;
    __shared__ float t4[70 * 70];
    __shared__ float ker[49];
    __shared__ float fin4[4];
    __shared__ float sAB[2];
    if (tid < 32) {   // finalize this block's GN coefs from 32 tile-partials x 2 channels
        int ch = (c & ~1) + (tid >> 4), k = tid & 15;
        int base = ((b << 5) + k) << 6;
        float s  = P1[base + ch] + P1[base + (16 << 6) + ch];
        float s2 = P2[base + ch] + P2[base + (16 << 6) + ch];
        #pragma unroll
        for (int off = 1; off < 16; off <<= 1) {
            s += __shfl_xor(s, off, 16); s2 += __shfl_xor(s2, off, 16);
        }
        if (k == 0) { fin4[tid >> 4] = s; fin4[2 + (tid >> 4)] = s2; }
    }
    // zero only the 3-wide halo (interior is fully overwritten below)
    for (int i = tid; i < 804; i += 256) {
        if (i < 420) {                       // top 3 + bottom 3 full-width rows
            int r = i / 70, cc = i - 70 * r;
            int row = (r < 3) ? r : (r + 64);
            t4[row * 70 + cc] = 0.f;
        } else {                             // left 3 + right 3 cols of rows 3..66
            int j = i - 420;
            int r = (j / 6) + 3, e = j - 6 * ((r - 3));
            int col = (e < 3) ? e : (e + 64);
            t4[r * 70 + col] = 0.f;
        }
    }
    if (tid < 49) ker[tid] = t_kernel[bc * 49 + tid];
    __syncthreads();
    if (tid == 0) {
        float S = fin4[0] + fin4[1], S2 = fin4[2] + fin4[3];
        float mean = S * (1.f / 8192.f);
        float var  = S2 * (1.f / 8192.f) - mean * mean;
        float inv  = rsqrtf(var + EPS);
        float a = gnw[c] * inv;
        sAB[0] = a; sAB[1] = gnb[c] - mean * a;
    }
    __syncthreads();
    float a = sAB[0], bb = sAB[1], tg = t_global[bc];
    const float4* sb4 = (const float4*)(sraw + ((long)bc << 12));
    for (int i4 = tid; i4 < 1024; i4 += 256) {
        float4 v4 = sb4[i4];
        int y = i4 >> 4, xx = (i4 & 15) << 2;
        float* dst = &t4[(y + 3) * 70 + xx + 3];
        float v;
        v = a * v4.x + bb; dst[0] = v > 0.f ? v : 0.f;
        v = a * v4.y + bb; dst[1] = v > 0.f ? v : 0.f;
        v = a * v4.z + bb; dst[2] = v > 0.f ? v : 0.f;
        v = a * v4.w + bb; dst[3] = v > 0.f ? v : 0.f;
    }
    __syncthreads();
    int x = tid & 63, ys = (tid >> 6) << 4;
    float acc[16];
    #pragma unroll
    for (int j = 0; j < 16; ++j) acc[j] = 0.f;
    #pragma unroll
    for (int kx = 0; kx < 7; ++kx) {
        float col[22];
        #pragma unroll
        for (int j = 0; j < 22; ++j) col[j] = t4[(ys + j) * 70 + x + kx];
        #pragma unroll
        for (int ky = 0; ky < 7; ++ky) {
            float kv = ker[ky * 7 + kx];
            #pragma unroll
            for (int j = 0; j < 16; ++j) acc[j] += kv * col[j + ky];
        }
    }
    unsigned short* ob = corr + ((long)bc << 12);
    #pragma unroll
    for (int j = 0; j < 16; ++j) {
        float sval = t4[(ys + j + 3) * 70 + x + 3];
        ob[((ys + j) << 6) + x] = f2bf(acc[j] + sval * tg);
    }
}

// ---------------- K5: conv3x3 via bf16 MFMA, reads NCHW bf16 corr directly ----------------
__global__ __launch_bounds__(256) void k5_mfma(
    const unsigned short* __restrict__ corrB, const unsigned short* __restrict__ wpk,
    unsigned short* __restrict__ y, float* __restrict__ P1, float* __restrict__ P2)
{
    int b = blockIdx.y, py0 = blockIdx.x << 1;
    int tid = threadIdx.x;
    int wave = tid >> 6, lane = tid & 63, q = lane >> 4, l15 = lane & 15;
    __shared__ short tile[16896];   // [row 4][col 66][ic 64] bf16, xor-swizzled (33792 B)
    __shared__ float Ys[4][64], Ys2[4][64];

    {
        int row = tid >> 6, ic = tid & 63;   // wave = one tile row, lane = ic
        int py = py0 - 1 + row;
        int rbase = (row * 66) << 6;
        int icblk = ic >> 3, icl = ic & 7;
        if (py >= 0 && py < 64) {
            const uint4* src = (const uint4*)(corrB + (((long)(b << 6) + ic) << 12) + (py << 6));
            #pragma unroll
            for (int c8 = 0; c8 < 8; ++c8) {
                uint4 u = src[c8];
                const unsigned short* us = (const unsigned short*)&u;
                #pragma unroll
                for (int e = 0; e < 8; ++e) {
                    int col = (c8 << 3) + e + 1;
                    int sw = icblk ^ (col & 7);
                    tile[rbase + (col << 6) + (sw << 3) + icl] = us[e];
                }
            }
        } else {
            for (int col = 1; col <= 64; ++col) {
                int sw = icblk ^ (col & 7);
                tile[rbase + (col << 6) + (sw << 3) + icl] = 0;
            }
        }
        // halo cols 0 (px=-1) and 65 (px=64) are always out of image -> zero
        tile[rbase + (icblk << 3) + icl] = 0;
        tile[rbase + (65 << 6) + (((icblk ^ 1) << 3)) + icl] = 0;
    }
    __syncthreads();

    floatx4 acc[2][4];
    #pragma unroll
    for (int i = 0; i < 2; ++i)
        #pragma unroll
        for (int ot = 0; ot < 4; ++ot) acc[i][ot] = (floatx4){0.f, 0.f, 0.f, 0.f};

    int pt0 = wave << 1;
    int rowb[2], colb[2];
    #pragma unroll
    for (int i = 0; i < 2; ++i) {
        int p = ((pt0 + i) << 4) + l15;
        rowb[i] = p >> 6;
        colb[i] = p & 63;
    }
    #pragma unroll
    for (int c = 0; c < 18; ++c) {
        const int tap = c >> 1, ky = tap / 3, kx = tap % 3, h = c & 1;
        short8 bfr[4], afr[2];
        #pragma unroll
        for (int ot = 0; ot < 4; ++ot)
            bfr[ot] = *(const short8*)(wpk + ((c << 6) + (ot << 4) + l15) * 32 + (q << 3));
        #pragma unroll
        for (int i = 0; i < 2; ++i) {
            int row = rowb[i] + ky, col = colb[i] + kx;
            int sw = ((h << 2) + q) ^ (col & 7);
            afr[i] = *(const short8*)&tile[((row * 66 + col) << 6) + (sw << 3)];
        }
        #pragma unroll
        for (int i = 0; i < 2; ++i)
            #pragma unroll
            for (int ot = 0; ot < 4; ++ot)
                acc[i][ot] = __builtin_amdgcn_mfma_f32_16x16x32_bf16(afr[i], bfr[ot], acc[i][ot], 0, 0, 0);
    }
    #pragma unroll
    for (int i = 0; i < 2; ++i) {
        #pragma unroll
        for (int r = 0; r < 4; ++r) {
            int p = ((pt0 + i) << 4) + (q << 2) + r;
            int py = py0 + (p >> 6), pxc = p & 63;
            int base = ((b << 12) + (py << 6) + pxc) << 6;
            #pragma unroll
            for (int ot = 0; ot < 4; ++ot)
                y[base + (ot << 4) + l15] = f2bf(acc[i][ot][r]);
        }
    }
    // fused GN stat partials: lane holds oc = ot*16 + l15
    #pragma unroll
    for (int ot = 0; ot < 4; ++ot) {
        float s = 0.f, s2 = 0.f;
        #pragma unroll
        for (int i = 0; i < 2; ++i)
            #pragma unroll
            for (int r = 0; r < 4; ++r) { float v = acc[i][ot][r]; s += v; s2 += v * v; }
        s += __shfl_xor(s, 16, 64); s2 += __shfl_xor(s2, 16, 64);
        s += __shfl_xor(s, 32, 64); s2 += __shfl_xor(s2, 32, 64);
        if (lane < 16) { Ys[wave][(ot << 4) + lane] = s; Ys2[wave][(ot << 4) + lane] = s2; }
    }
    __syncthreads();
    if (tid < 64) {
        float s  = Ys[0][tid] + Ys[1][tid] + Ys[2][tid] + Ys[3][tid];
        float s2 = Ys2[0][tid] + Ys2[1][tid] + Ys2[2][tid] + Ys2[3][tid];
        int idx = (((b << 5) + blockIdx.x) << 6) + tid;
        P1[idx] = s; P2[idx] = s2;
    }
}

// ---------------- K6: epilogue on NHWC bf16 y (inline y-GN finalize) ----------------
__global__ __launch_bounds__(256) void k6_nhwc(
    const unsigned short* __restrict__ y, const float* __restrict__ P1, const float* __restrict__ P2,
    const float* __restrict__ gnw, const float* __restrict__ gnb,
    const float* __restrict__ w2, const float* __restrict__ b2, float* __restrict__ out)
{
    int b = blockIdx.y;
    int px0 = blockIdx.x << 7;
    int tid = threadIdx.x, wave = tid >> 6, lane = tid & 63;
    __shared__ float sA[64], sB[64];
    if (tid < 64) {
        int c = tid;
        float s = 0.f, s2 = 0.f;
        for (int t = 0; t < 32; ++t) {
            int idx = (((b << 5) + t) << 6) + c;
            s += P1[idx]; s2 += P2[idx];
        }
        float sp = __shfl_xor(s, 1, 64), s2p = __shfl_xor(s2, 1, 64);
        float S = s + sp, S2 = s2 + s2p;
        float mean = S * (1.f / 8192.f);
        float var  = S2 * (1.f / 8192.f) - mean * mean;
        float inv  = rsqrtf(var + EPS);
        float a = gnw[c] * inv;
        sA[c] = a; sB[c] = gnb[c] - mean * a;
    }
    __syncthreads();
    int ocp = lane & 31, ph = lane >> 5;
    int c0 = 2 * ocp;
    float a0 = sA[c0],     b0 = sB[c0],     w20 = w2[c0];
    float a1 = sA[c0 + 1], b1 = sB[c0 + 1], w21 = w2[c0 + 1];
    float bias = b2[0];
    const unsigned* yp = (const unsigned*)y;
    for (int i = 0; i < 16; ++i) {
        int px = px0 + (i << 3) + (wave << 1) + ph;
        unsigned u = yp[(((b << 12) + px) << 5) + ocp];
        float f0 = bf2f((unsigned short)(u & 0xFFFF));
        float f1 = bf2f((unsigned short)(u >> 16));
        float v0 = a0 * f0 + b0; v0 = v0 > 0.f ? v0 : 0.f;
        float v1 = a1 * f1 + b1; v1 = v1 > 0.f ? v1 : 0.f;
        float val = w20 * v0 + w21 * v1;
        #pragma unroll
        for (int m = 16; m >= 1; m >>= 1) val += __shfl_xor(val, m, 64);
        if (ocp == 0) out[(b << 12) + px] = val + bias;
    }
}

extern "C" void kernel_launch(void* const* d_in, const int* in_sizes, int n_in,
                              void* d_out, int out_size, void* d_ws, size_t ws_size,
                              hipStream_t stream)
{
    const float* tmpl   = (const float*)d_in[0];
    const float* search = (const float*)d_in[1];
    const float* w_t    = (const float*)d_in[2];
    const float* gn_t_w = (const float*)d_in[3];
    const float* gn_t_b = (const float*)d_in[4];
    const float* w_s    = (const float*)d_in[5];
    const float* gn_s_w = (const float*)d_in[6];
    const float* gn_s_b = (const float*)d_in[7];
    const float* w_p1   = (const float*)d_in[8];
    const float* gn_p_w = (const float*)d_in[9];
    const float* gn_p_b = (const float*)d_in[10];
    const float* w_p2   = (const float*)d_in[11];
    const float* b_p2   = (const float*)d_in[12];
    float* out = (float*)d_out;
    float* ws  = (float*)d_ws;

    float* TG   = ws;                    // 2048
    float* TK   = ws + 2048;             // 100352 -> ends 102400
    float* P1   = ws + 102400;           // 65536 (32b x 32 tiles x 64 oc) -> ends 167936
    float* P2   = ws + 167936;           // 65536 -> ends 233472
    unsigned short* WPK = (unsigned short*)(ws + 233472);   // 36864 bf16 -> ends 251904
    float* SRAW = ws + 262144;           // 8388608 floats (32 MB) -> ends 8650752
    unsigned short* CORRB = (unsigned short*)(ws + 8650752); // 4194304 bf16 (8 MB)
    // overlays (timeline-disjoint):
    unsigned short* WSB   = (unsigned short*)CORRB;          // k_pack writes, k2x reads; k4 overwrites
    unsigned short* YRAW  = (unsigned short*)SRAW;           // k5 writes after SRAW dead (k4 last reader)

    k_pack<<<208, 256, 0, stream>>>(w_s, WSB, w_p1, WPK);
    k2x<<<1280, 256, 0, stream>>>(search, WSB, SRAW, P1, P2,
                                  tmpl, w_t, gn_t_w, gn_t_b, TG, TK);
    k4_corr<<<2048, 256, 0, stream>>>(SRAW, P1, P2, gn_s_w, gn_s_b, TG, TK, CORRB);
    k5_mfma<<<dim3(32, 32), 256, 0, stream>>>(CORRB, WPK, YRAW, P1, P2);
    k6_nhwc<<<dim3(32, 32), 256, 0, stream>>>(YRAW, P1, P2, gn_p_w, gn_p_b, w_p2, b_p2, out);
}

// Round 10
// 297.388 us; speedup vs baseline: 2.0795x; 1.0283x over previous
//
#include <hip/hip_runtime.h>

#define EPS 1e-5f

// B=32, C=256, CC=64, template 14x14, search 64x64, K=7, 32 groups (2ch/group)

typedef __attribute__((ext_vector_type(8))) short short8;
typedef __attribute__((ext_vector_type(4))) float floatx4;

__device__ __forceinline__ unsigned short f2bf(float x) {
    union { float f; unsigned u; } v; v.f = x;
    unsigned r = v.u + 0x7FFFu + ((v.u >> 16) & 1u);   // RNE
    return (unsigned short)(r >> 16);
}
__device__ __forceinline__ float bf2f(unsigned short h) {
    union { unsigned u; float f; } v; v.u = ((unsigned)h) << 16;
    return v.f;
}

// ---------------- K_PACK: w_s and w_p1 fp32 -> bf16 prepack ----------------
__global__ __launch_bounds__(256) void k_pack(
    const float* __restrict__ w_s, unsigned short* __restrict__ wsb,
    const float* __restrict__ w1, unsigned short* __restrict__ wpk)
{
    int blk = blockIdx.x;
    if (blk < 64) {
        int i = blk * 256 + threadIdx.x;
        wsb[i] = f2bf(w_s[i]);
    } else {
        int i = (blk - 64) * 256 + threadIdx.x;
        if (i < 36864) {
            int c = i >> 11;
            int rem = i & 2047;
            int oc = rem >> 5;
            int k = rem & 31;
            int tap = c >> 1;
            int ic = ((c & 1) << 5) + k;
            wpk[i] = f2bf(w1[oc * 576 + ic * 9 + tap]);
        }
    }
}

// ---------------- K2X: template path (blocks 0-255) hidden under search conv1x1 MFMA (blocks 256-1279) ----------------
// Template path now stages its weight chunk into LDS (kills the global-scalar-load-in-inner-loop).
// MFMA part: 128 px x 64 oc per block, K=256, double-buffered LDS, fused GN stat partials.
__global__ __launch_bounds__(256) void k2x(
    const float* __restrict__ x, const unsigned short* __restrict__ wsb,
    float* __restrict__ sraw, float* __restrict__ P1, float* __restrict__ P2,
    const float* __restrict__ tmpl, const float* __restrict__ w_t,
    const float* __restrict__ gnw, const float* __restrict__ gnb,
    float* __restrict__ t_global, float* __restrict__ t_kernel)
{
    int tid = threadIdx.x;
    __shared__ __align__(16) char smem[34816];

    if (blockIdx.x < 256) {
        // ======== template path: conv1x1(14x14) + GN + ReLU + pooled outputs ========
        int b = blockIdx.x >> 3, h = blockIdx.x & 7;   // h: eighth of oc (8 oc)
        float (*Xs)[200] = (float(*)[200])smem;              // 25600 B
        float (*T0)[200] = (float(*)[200])(smem + 25600);    // 6400 B -> ends 32000
        float* sums  = (float*)(smem + 32000);
        float* sumsq = (float*)(smem + 32032);
        float* Ac    = (float*)(smem + 32064);
        float* Bb    = (float*)(smem + 32096);
        float (*Wv)[32] = (float(*)[32])(smem + 32128);      // 1024 B -> ends 33152
        float acc[8];
        #pragma unroll
        for (int o = 0; o < 8; ++o) acc[o] = 0.f;
        const float* wb = w_t + (h * 8) * 256;
        const float* tb = tmpl + b * 50176;
        int p = tid;
        for (int chunk = 0; chunk < 8; ++chunk) {
            __syncthreads();
            #pragma unroll
            for (int j = 0; j < 7; ++j) {
                int f4 = tid + (j << 8);
                if (f4 < 1568) {                        // 32 rows x 49 float4
                    int ic = f4 / 49, px4 = (f4 - ic * 49) << 2;
                    float4 v = *(const float4*)(tb + (chunk * 32 + ic) * 196 + px4);
                    *(float4*)&Xs[ic][px4] = v;
                }
            }
            if (tid < 64) {   // stage this chunk's weights: 8 oc x 32 ic
                int o = tid >> 3, cc4 = (tid & 7) << 2;
                float4 wv = *(const float4*)(wb + o * 256 + chunk * 32 + cc4);
                *(float4*)&Wv[o][cc4] = wv;
            }
            __syncthreads();
            if (p < 196) {
                for (int cc = 0; cc < 32; ++cc) {
                    float xv = Xs[cc][p];
                    #pragma unroll
                    for (int o = 0; o < 8; ++o)
                        acc[o] += xv * Wv[o][cc];
                }
            }
        }
        __syncthreads();
        if (p < 196) {
            #pragma unroll
            for (int o = 0; o < 8; ++o) T0[o][p] = acc[o];
        }
        __syncthreads();
        if (tid < 128) {   // 16 lanes per channel
            int c = tid >> 4, part = tid & 15;
            float s = 0.f, s2 = 0.f;
            for (int qq = part; qq < 196; qq += 16) { float v = T0[c][qq]; s += v; s2 += v * v; }
            #pragma unroll
            for (int off = 1; off < 16; off <<= 1) {
                s += __shfl_xor(s, off, 16); s2 += __shfl_xor(s2, off, 16);
            }
            if (part == 0) { sums[c] = s; sumsq[c] = s2; }
        }
        __syncthreads();
        if (tid < 4) {   // group = channel pair, both in this block
            float S  = sums[2 * tid] + sums[2 * tid + 1];
            float S2 = sumsq[2 * tid] + sumsq[2 * tid + 1];
            float mean = S * (1.f / 392.f);
            float var  = S2 * (1.f / 392.f) - mean * mean;
            float inv  = rsqrtf(var + EPS);
            for (int e = 0; e < 2; ++e) {
                int c = 2 * tid + e, gc = h * 8 + c;
                float a = gnw[gc] * inv;
                Ac[c] = a; Bb[c] = gnb[gc] - mean * a;
            }
        }
        __syncthreads();
        if (p < 196) {
            #pragma unroll
            for (int o = 0; o < 8; ++o) {
                float v = Ac[o] * T0[o][p] + Bb[o];
                T0[o][p] = v > 0.f ? v : 0.f;
            }
        }
        __syncthreads();
        if (tid < 128) {
            int c = tid >> 4, part = tid & 15, gc = h * 8 + c;
            float s = 0.f;
            for (int qq = part; qq < 196; qq += 16) s += T0[c][qq];
            #pragma unroll
            for (int off = 1; off < 16; off <<= 1) s += __shfl_xor(s, off, 16);
            if (part == 0) t_global[b * 64 + gc] = s * (1.f / 196.f);
            for (int t = part; t < 49; t += 16) {
                int ky = t / 7, kx = t - 7 * ky;
                float v = T0[c][(2 * ky) * 14 + 2 * kx]     + T0[c][(2 * ky) * 14 + 2 * kx + 1]
                        + T0[c][(2 * ky + 1) * 14 + 2 * kx] + T0[c][(2 * ky + 1) * 14 + 2 * kx + 1];
                t_kernel[(b * 64 + gc) * 49 + t] = v * 0.25f;
            }
        }
        return;
    }

    // ======== search conv1x1 MFMA ========
    int mblk = blockIdx.x - 256;
    int b = mblk >> 5, p0 = (mblk & 31) << 7;
    int wave = tid >> 6, lane = tid & 63, q = lane >> 4, l15 = lane & 15;
    short (*tile)[128 * 64] = (short(*)[128 * 64])smem;     // 2 x 16384 B
    float (*Ps)[64]  = (float(*)[64])(smem + 32768);        // 1024 B
    float (*Ps2)[64] = (float(*)[64])(smem + 33792);        // 1024 B -> ends 34816

    floatx4 acc[2][4];
    #pragma unroll
    for (int i = 0; i < 2; ++i)
        #pragma unroll
        for (int mt = 0; mt < 4; ++mt) acc[i][mt] = (floatx4){0.f, 0.f, 0.f, 0.f};

    int pxq = (tid & 31) << 2;     // px base (4 consecutive px per thread)
    int icr = tid >> 5;            // ic group 0..7 (8 consecutive ic per thread)
    const float* xb = x + ((long)b << 20) + p0 + pxq;
    float4 L[8];
    #pragma unroll
    for (int i = 0; i < 8; ++i)
        L[i] = *(const float4*)(xb + ((long)((icr << 3) + i) << 12));
    // stage chunk 0 into buf 0
    #pragma unroll
    for (int j = 0; j < 4; ++j) {
        int px = pxq + j;
        short8 s8;
        #pragma unroll
        for (int e = 0; e < 8; ++e) s8[e] = (short)f2bf(((const float*)&L[e])[j]);
        int sw = icr ^ (px & 7);
        *(short8*)&tile[0][(px << 6) + (sw << 3)] = s8;
    }
    #pragma unroll
    for (int chunk = 0; chunk < 4; ++chunk) {           // 64 ic per chunk
        const int cur = chunk & 1;
        __syncthreads();   // buf[cur] staged; prior reads of buf[cur^1] done
        if (chunk < 3) {   // issue next chunk's loads; drain under MFMA below
            #pragma unroll
            for (int i = 0; i < 8; ++i)
                L[i] = *(const float4*)(xb + ((long)(((chunk + 1) << 6) + (icr << 3) + i) << 12));
        }
        #pragma unroll
        for (int kq = 0; kq < 2; ++kq) {                // 32-ic MFMA chunks
            short8 afr[4], bfr[2];
            int kbase = (chunk << 6) + (kq << 5) + (q << 3);
            #pragma unroll
            for (int mt = 0; mt < 4; ++mt)
                afr[mt] = *(const short8*)(wsb + ((mt << 4) + l15) * 256 + kbase);
            #pragma unroll
            for (int i = 0; i < 2; ++i) {
                int px = (((wave << 1) + i) << 4) + l15;
                int sw = ((kq << 2) + q) ^ (px & 7);
                bfr[i] = *(const short8*)&tile[cur][(px << 6) + (sw << 3)];
            }
            #pragma unroll
            for (int i = 0; i < 2; ++i)
                #pragma unroll
                for (int mt = 0; mt < 4; ++mt)
                    acc[i][mt] = __builtin_amdgcn_mfma_f32_16x16x32_bf16(afr[mt], bfr[i], acc[i][mt], 0, 0, 0);
        }
        if (chunk < 3) {   // stage next chunk into the other buffer (safe: post-sync)
            #pragma unroll
            for (int j = 0; j < 4; ++j) {
                int px = pxq + j;
                short8 s8;
                #pragma unroll
                for (int e = 0; e < 8; ++e) s8[e] = (short)f2bf(((const float*)&L[e])[j]);
                int sw = icr ^ (px & 7);
                *(short8*)&tile[cur ^ 1][(px << 6) + (sw << 3)] = s8;
            }
        }
    }
    // D: col(lane&15)=px-in-frag, row(q*4+r)=oc-in-tile
    float* ob = sraw + ((long)b << 18) + p0;
    #pragma unroll
    for (int i = 0; i < 2; ++i) {
        int pxb = ((wave << 1) + i) << 4;
        #pragma unroll
        for (int mt = 0; mt < 4; ++mt)
            #pragma unroll
            for (int r = 0; r < 4; ++r) {
                int oc = (mt << 4) + (q << 2) + r;
                ob[(oc << 12) + pxb + l15] = acc[i][mt][r];
            }
    }
    // fused GN stat partials
    #pragma unroll
    for (int mt = 0; mt < 4; ++mt) {
        #pragma unroll
        for (int r = 0; r < 4; ++r) {
            float s = 0.f, s2 = 0.f;
            #pragma unroll
            for (int i = 0; i < 2; ++i) { float v = acc[i][mt][r]; s += v; s2 += v * v; }
            #pragma unroll
            for (int off = 1; off < 16; off <<= 1) {
                s  += __shfl_xor(s, off, 64);
                s2 += __shfl_xor(s2, off, 64);
            }
            if (l15 == 0) {
                int oc = (mt << 4) + (q << 2) + r;
                Ps[wave][oc] = s; Ps2[wave][oc] = s2;
            }
        }
    }
    __syncthreads();
    if (tid < 64) {
        float s  = Ps[0][tid] + Ps[1][tid] + Ps[2][tid] + Ps[3][tid];
        float s2 = Ps2[0][tid] + Ps2[1][tid] + Ps2[2][tid] + Ps2[3][tid];
        int idx = (((b << 5) + (mblk & 31)) << 6) + tid;
        P1[idx] = s; P2[idx] = s2;
    }
}

// ---------------- K4: corr = s*t_global + depthwise7x7 -> bf16 NCHW (inline s-GN finalize) ----------------
__global__ __launch_bounds__(256) void k4_corr(
    const float* __restrict__ sraw, const float* __restrict__ P1, const float* __restrict__ P2,
    const float* __restrict__ gnw, const float* __restrict__ gnb,
    const float* __restrict__ t_global, const float* __restrict__ t_kernel,
    unsigned short* __restrict__ corr)
{
    int bc = blockIdx.x;
    int b = bc >> 6, c = bc & 63;
    int tid = threadIdx.x;
    __shared__ float t4[70 * 70];
    __shared__ float ker[49];
    __shared__ float fin4[4];
    __shared__ float sAB[2];
    if (tid < 32) {   // finalize this block's GN coefs from 32 tile-partials x 2 channels
        int ch = (c & ~1) + (tid >> 4), k = tid & 15;
        int base = ((b << 5) + k) << 6;
        float s  = P1[base + ch] + P1[base + (16 << 6) + ch];
        float s2 = P2[base + ch] + P2[base + (16 << 6) + ch];
        #pragma unroll
        for (int off = 1; off < 16; off <<= 1) {
            s += __shfl_xor(s, off, 16); s2 += __shfl_xor(s2, off, 16);
        }
        if (k == 0) { fin4[tid >> 4] = s; fin4[2 + (tid >> 4)] = s2; }
    }
    // zero only the 3-wide halo (interior is fully overwritten below)
    for (int i = tid; i < 804; i += 256) {
        if (i < 420) {                       // top 3 + bottom 3 full-width rows
            int r = i / 70, cc = i - 70 * r;
            int row = (r < 3) ? r : (r + 64);
            t4[row * 70 + cc] = 0.f;
        } else {                             // left 3 + right 3 cols of rows 3..66
            int j = i - 420;
            int r = (j / 6) + 3, e = j - 6 * ((r - 3));
            int col = (e < 3) ? e : (e + 64);
            t4[r * 70 + col] = 0.f;
        }
    }
    if (tid < 49) ker[tid] = t_kernel[bc * 49 + tid];
    __syncthreads();
    if (tid == 0) {
        float S = fin4[0] + fin4[1], S2 = fin4[2] + fin4[3];
        float mean = S * (1.f / 8192.f);
        float var  = S2 * (1.f / 8192.f) - mean * mean;
        float inv  = rsqrtf(var + EPS);
        float a = gnw[c] * inv;
        sAB[0] = a; sAB[1] = gnb[c] - mean * a;
    }
    __syncthreads();
    float a = sAB[0], bb = sAB[1], tg = t_global[bc];
    const float4* sb4 = (const float4*)(sraw + ((long)bc << 12));
    for (int i4 = tid; i4 < 1024; i4 += 256) {
        float4 v4 = sb4[i4];
        int y = i4 >> 4, xx = (i4 & 15) << 2;
        float* dst = &t4[(y + 3) * 70 + xx + 3];
        float v;
        v = a * v4.x + bb; dst[0] = v > 0.f ? v : 0.f;
        v = a * v4.y + bb; dst[1] = v > 0.f ? v : 0.f;
        v = a * v4.z + bb; dst[2] = v > 0.f ? v : 0.f;
        v = a * v4.w + bb; dst[3] = v > 0.f ? v : 0.f;
    }
    __syncthreads();
    int x = tid & 63, ys = (tid >> 6) << 4;
    float acc[16];
    #pragma unroll
    for (int j = 0; j < 16; ++j) acc[j] = 0.f;
    #pragma unroll
    for (int kx = 0; kx < 7; ++kx) {
        float col[22];
        #pragma unroll
        for (int j = 0; j < 22; ++j) col[j] = t4[(ys + j) * 70 + x + kx];
        #pragma unroll
        for (int ky = 0; ky < 7; ++ky) {
            float kv = ker[ky * 7 + kx];
            #pragma unroll
            for (int j = 0; j < 16; ++j) acc[j] += kv * col[j + ky];
        }
    }
    unsigned short* ob = corr + ((long)bc << 12);
    #pragma unroll
    for (int j = 0; j < 16; ++j) {
        float sval = t4[(ys + j + 3) * 70 + x + 3];
        ob[((ys + j) << 6) + x] = f2bf(acc[j] + sval * tg);
    }
}

// ---------------- K5: conv3x3 via bf16 MFMA, reads NCHW bf16 corr directly ----------------
__global__ __launch_bounds__(256) void k5_mfma(
    const unsigned short* __restrict__ corrB, const unsigned short* __restrict__ wpk,
    unsigned short* __restrict__ y, float* __restrict__ P1, float* __restrict__ P2)
{
    int b = blockIdx.y, py0 = blockIdx.x << 1;
    int tid = threadIdx.x;
    int wave = tid >> 6, lane = tid & 63, q = lane >> 4, l15 = lane & 15;
    __shared__ short tile[16896];   // [row 4][col 66][ic 64] bf16, xor-swizzled (33792 B)
    __shared__ float Ys[4][64], Ys2[4][64];

    {
        int row = tid >> 6, ic = tid & 63;   // wave = one tile row, lane = ic
        int py = py0 - 1 + row;
        int rbase = (row * 66) << 6;
        int icblk = ic >> 3, icl = ic & 7;
        if (py >= 0 && py < 64) {
            const uint4* src = (const uint4*)(corrB + (((long)(b << 6) + ic) << 12) + (py << 6));
            #pragma unroll
            for (int c8 = 0; c8 < 8; ++c8) {
                uint4 u = src[c8];
                const unsigned short* us = (const unsigned short*)&u;
                #pragma unroll
                for (int e = 0; e < 8; ++e) {
                    int col = (c8 << 3) + e + 1;
                    int sw = icblk ^ (col & 7);
                    tile[rbase + (col << 6) + (sw << 3) + icl] = us[e];
                }
            }
        } else {
            for (int col = 1; col <= 64; ++col) {
                int sw = icblk ^ (col & 7);
                tile[rbase + (col << 6) + (sw << 3) + icl] = 0;
            }
        }
        // halo cols 0 (px=-1) and 65 (px=64) are always out of image -> zero
        tile[rbase + (icblk << 3) + icl] = 0;
        tile[rbase + (65 << 6) + (((icblk ^ 1) << 3)) + icl] = 0;
    }
    __syncthreads();

    floatx4 acc[2][4];
    #pragma unroll
    for (int i = 0; i < 2; ++i)
        #pragma unroll
        for (int ot = 0; ot < 4; ++ot) acc[i][ot] = (floatx4){0.f, 0.f, 0.f, 0.f};

    int pt0 = wave << 1;
    int rowb[2], colb[2];
    #pragma unroll
    for (int i = 0; i < 2; ++i) {
        int p = ((pt0 + i) << 4) + l15;
        rowb[i] = p >> 6;
        colb[i] = p & 63;
    }
    #pragma unroll
    for (int c = 0; c < 18; ++c) {
        const int tap = c >> 1, ky = tap / 3, kx = tap % 3, h = c & 1;
        short8 bfr[4], afr[2];
        #pragma unroll
        for (int ot = 0; ot < 4; ++ot)
            bfr[ot] = *(const short8*)(wpk + ((c << 6) + (ot << 4) + l15) * 32 + (q << 3));
        #pragma unroll
        for (int i = 0; i < 2; ++i) {
            int row = rowb[i] + ky, col = colb[i] + kx;
            int sw = ((h << 2) + q) ^ (col & 7);
            afr[i] = *(const short8*)&tile[((row * 66 + col) << 6) + (sw << 3)];
        }
        #pragma unroll
        for (int i = 0; i < 2; ++i)
            #pragma unroll
            for (int ot = 0; ot < 4; ++ot)
                acc[i][ot] = __builtin_amdgcn_mfma_f32_16x16x32_bf16(afr[i], bfr[ot], acc[i][ot], 0, 0, 0);
    }
    #pragma unroll
    for (int i = 0; i < 2; ++i) {
        #pragma unroll
        for (int r = 0; r < 4; ++r) {
            int p = ((pt0 + i) << 4) + (q << 2) + r;
            int py = py0 + (p >> 6), pxc = p & 63;
            int base = ((b << 12) + (py << 6) + pxc) << 6;
            #pragma unroll
            for (int ot = 0; ot < 4; ++ot)
                y[base + (ot << 4) + l15] = f2bf(acc[i][ot][r]);
        }
    }
    // fused GN stat partials: lane holds oc = ot*16 + l15
    #pragma unroll
    for (int ot = 0; ot < 4; ++ot) {
        float s = 0.f, s2 = 0.f;
        #pragma unroll
        for (int i = 0; i < 2; ++i)
            #pragma unroll
            for (int r = 0; r < 4; ++r) { float v = acc[i][ot][r]; s += v; s2 += v * v; }
        s += __shfl_xor(s, 16, 64); s2 += __shfl_xor(s2, 16, 64);
        s += __shfl_xor(s, 32, 64); s2 += __shfl_xor(s2, 32, 64);
        if (lane < 16) { Ys[wave][(ot << 4) + lane] = s; Ys2[wave][(ot << 4) + lane] = s2; }
    }
    __syncthreads();
    if (tid < 64) {
        float s  = Ys[0][tid] + Ys[1][tid] + Ys[2][tid] + Ys[3][tid];
        float s2 = Ys2[0][tid] + Ys2[1][tid] + Ys2[2][tid] + Ys2[3][tid];
        int idx = (((b << 5) + blockIdx.x) << 6) + tid;
        P1[idx] = s; P2[idx] = s2;
    }
}

// ---------------- K6: epilogue on NHWC bf16 y (inline y-GN finalize) ----------------
__global__ __launch_bounds__(256) void k6_nhwc(
    const unsigned short* __restrict__ y, const float* __restrict__ P1, const float* __restrict__ P2,
    const float* __restrict__ gnw, const float* __restrict__ gnb,
    const float* __restrict__ w2, const float* __restrict__ b2, float* __restrict__ out)
{
    int b = blockIdx.y;
    int px0 = blockIdx.x << 7;
    int tid = threadIdx.x, wave = tid >> 6, lane = tid & 63;
    __shared__ float sA[64], sB[64];
    if (tid < 64) {
        int c = tid;
        float s = 0.f, s2 = 0.f;
        for (int t = 0; t < 32; ++t) {
            int idx = (((b << 5) + t) << 6) + c;
            s += P1[idx]; s2 += P2[idx];
        }
        float sp = __shfl_xor(s, 1, 64), s2p = __shfl_xor(s2, 1, 64);
        float S = s + sp, S2 = s2 + s2p;
        float mean = S * (1.f / 8192.f);
        float var  = S2 * (1.f / 8192.f) - mean * mean;
        float inv  = rsqrtf(var + EPS);
        float a = gnw[c] * inv;
        sA[c] = a; sB[c] = gnb[c] - mean * a;
    }
    __syncthreads();
    int ocp = lane & 31, ph = lane >> 5;
    int c0 = 2 * ocp;
    float a0 = sA[c0],     b0 = sB[c0],     w20 = w2[c0];
    float a1 = sA[c0 + 1], b1 = sB[c0 + 1], w21 = w2[c0 + 1];
    float bias = b2[0];
    const unsigned* yp = (const unsigned*)y;
    for (int i = 0; i < 16; ++i) {
        int px = px0 + (i << 3) + (wave << 1) + ph;
        unsigned u = yp[(((b << 12) + px) << 5) + ocp];
        float f0 = bf2f((unsigned short)(u & 0xFFFF));
        float f1 = bf2f((unsigned short)(u >> 16));
        float v0 = a0 * f0 + b0; v0 = v0 > 0.f ? v0 : 0.f;
        float v1 = a1 * f1 + b1; v1 = v1 > 0.f ? v1 : 0.f;
        float val = w20 * v0 + w21 * v1;
        #pragma unroll
        for (int m = 16; m >= 1; m >>= 1) val += __shfl_xor(val, m, 64);
        if (ocp == 0) out[(b << 12) + px] = val + bias;
    }
}

extern "C" void kernel_launch(void* const* d_in, const int* in_sizes, int n_in,
                              void* d_out, int out_size, void* d_ws, size_t ws_size,
                              hipStream_t stream)
{
    const float* tmpl   = (const float*)d_in[0];
    const float* search = (const float*)d_in[1];
    const float* w_t    = (const float*)d_in[2];
    const float* gn_t_w = (const float*)d_in[3];
    const float* gn_t_b = (const float*)d_in[4];
    const float* w_s    = (const float*)d_in[5];
    const float* gn_s_w = (const float*)d_in[6];
    const float* gn_s_b = (const float*)d_in[7];
    const float* w_p1   = (const float*)d_in[8];
    const float* gn_p_w = (const float*)d_in[9];
    const float* gn_p_b = (const float*)d_in[10];
    const float* w_p2   = (const float*)d_in[11];
    const float* b_p2   = (const float*)d_in[12];
    float* out = (float*)d_out;
    float* ws  = (float*)d_ws;

    float* TG   = ws;                    // 2048
    float* TK   = ws + 2048;             // 100352 -> ends 102400
    float* P1   = ws + 102400;           // 65536 (32b x 32 tiles x 64 oc) -> ends 167936
    float* P2   = ws + 167936;           // 65536 -> ends 233472
    unsigned short* WPK = (unsigned short*)(ws + 233472);   // 36864 bf16 -> ends 251904
    float* SRAW = ws + 262144;           // 8388608 floats (32 MB) -> ends 8650752
    unsigned short* CORRB = (unsigned short*)(ws + 8650752); // 4194304 bf16 (8 MB)
    // overlays (timeline-disjoint):
    unsigned short* WSB   = (unsigned short*)CORRB;          // k_pack writes, k2x reads; k4 overwrites
    unsigned short* YRAW  = (unsigned short*)SRAW;           // k5 writes after SRAW dead (k4 last reader)

    k_pack<<<208, 256, 0, stream>>>(w_s, WSB, w_p1, WPK);
    k2x<<<1280, 256, 0, stream>>>(search, WSB, SRAW, P1, P2,
                                  tmpl, w_t, gn_t_w, gn_t_b, TG, TK);
    k4_corr<<<2048, 256, 0, stream>>>(SRAW, P1, P2, gn_s_w, gn_s_b, TG, TK, CORRB);
    k5_mfma<<<dim3(32, 32), 256, 0, stream>>>(CORRB, WPK, YRAW, P1, P2);
    k6_nhwc<<<dim3(32, 32), 256, 0, stream>>>(YRAW, P1, P2, gn_p_w, gn_p_b, w_p2, b_p2, out);
}